// Round 9
// baseline (152.583 us; speedup 1.0000x reference)
//
#include <hip/hip_runtime.h>

typedef unsigned short u16;
typedef __bf16 bf16x8 __attribute__((ext_vector_type(8)));
typedef float f32x4 __attribute__((ext_vector_type(4)));

#define B_ 2
#define S_ 2048
#define E_ 1024
#define H_ 16
#define D_ 64
#define M_ (B_ * S_)   // 4096

__device__ inline u16 f2bf(float f) {
  union { float f; unsigned int u; } c; c.f = f;
  unsigned int u = c.u;
  return (u16)((u + 0x7FFFu + ((u >> 16) & 1u)) >> 16);
}

__device__ inline f32x4 mfma16(bf16x8 a, bf16x8 b, f32x4 c) {
  return __builtin_amdgcn_mfma_f32_16x16x32_bf16(a, b, c, 0, 0, 0);
}

__device__ inline void gload16(const void* g, void* lds) {
  __builtin_amdgcn_global_load_lds(
      (const __attribute__((address_space(1))) unsigned int*)g,
      (__attribute__((address_space(3))) unsigned int*)lds, 16, 0, 0);
}

// ---------------- fp32 -> bf16 conversion (all 7 tensors, one launch) -------
struct CvtArgs {
  const float* src[7];
  u16* dst[7];
  int n[7];
};

__global__ __launch_bounds__(256) void cvt_kernel(CvtArgs a) {
  const int arr = blockIdx.y;
  const int n = a.n[arr];
  const float* __restrict__ s = a.src[arr];
  u16* __restrict__ d = a.dst[arr];
  const int stride = gridDim.x * blockDim.x;
  for (int i = blockIdx.x * blockDim.x + threadIdx.x; i * 4 < n; i += stride) {
    const float4 f = *(const float4*)(s + 4 * i);
    ushort4 o;
    o.x = f2bf(f.x); o.y = f2bf(f.y); o.z = f2bf(f.z); o.w = f2bf(f.w);
    *(ushort4*)(d + 4 * i) = o;
  }
}

// ---------------- fused QKV projection: 3 GEMMs in one launch ---------------
__global__ __launch_bounds__(256, 4) void qkv_gemm(
    const u16* __restrict__ qb, const u16* __restrict__ kb,
    const u16* __restrict__ vbp, const u16* __restrict__ Wqb,
    const u16* __restrict__ Wkb, const u16* __restrict__ Wvb,
    u16* __restrict__ Qh, u16* __restrict__ Kh, u16* __restrict__ Vt) {
  constexpr int BM = 128, BN = 128, BK = 32;
  __shared__ alignas(16) u16 As[BM * BK];
  __shared__ alignas(16) u16 Bs[BN * BK];
  const int z = blockIdx.z;
  const u16* A  = (z == 0) ? qb  : (z == 1) ? kb  : vbp;
  const u16* Bt = (z == 0) ? Wqb : (z == 1) ? Wkb : Wvb;
  u16* outp     = (z == 0) ? Qh  : (z == 1) ? Kh  : Vt;

  const int tid = threadIdx.x;
  const int wave = tid >> 6, lane = tid & 63;
  const int m0 = blockIdx.y * BM, n0 = blockIdx.x * BN;
  const int wm = (wave >> 1) * 64, wn = (wave & 1) * 64;
  const int lrow = lane >> 2, lcol = (lane & 3) * 8;

  f32x4 acc[4][4] = {};

  for (int k0 = 0; k0 < E_; k0 += BK) {
#pragma unroll
    for (int i = 0; i < 2; ++i) {
      const int chunk = wave * 2 + i;  // 0..7, 16 rows each
      const int row = chunk * 16 + lrow;
      gload16(A + (size_t)(m0 + row) * E_ + k0 + lcol, As + chunk * 16 * BK);
      gload16(Bt + (size_t)(n0 + row) * E_ + k0 + lcol, Bs + chunk * 16 * BK);
    }
    __syncthreads();
    bf16x8 af[4], bfr[4];
#pragma unroll
    for (int mi = 0; mi < 4; ++mi)
      af[mi] = *(const bf16x8*)&As[(wm + mi * 16 + (lane & 15)) * BK + 8 * (lane >> 4)];
#pragma unroll
    for (int ni = 0; ni < 4; ++ni)
      bfr[ni] = *(const bf16x8*)&Bs[(wn + ni * 16 + (lane & 15)) * BK + 8 * (lane >> 4)];
#pragma unroll
    for (int mi = 0; mi < 4; ++mi)
#pragma unroll
      for (int ni = 0; ni < 4; ++ni)
        acc[mi][ni] = mfma16(af[mi], bfr[ni], acc[mi][ni]);
    __syncthreads();
  }

#pragma unroll
  for (int mi = 0; mi < 4; ++mi)
#pragma unroll
    for (int ni = 0; ni < 4; ++ni)
#pragma unroll
      for (int r = 0; r < 4; ++r) {
        const int m = m0 + wm + mi * 16 + ((lane >> 4) << 2) + r;
        const int n = n0 + wn + ni * 16 + (lane & 15);
        const float v = acc[mi][ni][r];
        const int b = m >> 11, s = m & (S_ - 1), h = n >> 6, d = n & 63;
        if (z != 2) {
          outp[((((size_t)b * H_ + h) * S_ + s) << 6) + d] = f2bf(v);
        } else {
          outp[(((size_t)b * H_ + h) * D_ + d) * S_ + s] = f2bf(v);
        }
      }
}

// ---------------- output projection GEMM (BM=64 -> 512 blocks = 2/CU) ------
__global__ __launch_bounds__(256, 4) void oproj_gemm(
    const u16* __restrict__ A, const u16* __restrict__ Bt,
    const float* __restrict__ bias, float* __restrict__ outp) {
  constexpr int BM = 64, BN = 128, BK = 32;
  constexpr int ACH = BM / 16, NCH = ACH + BN / 16;  // 4 + 8 = 12
  __shared__ alignas(16) u16 As[BM * BK];
  __shared__ alignas(16) u16 Bs[BN * BK];
  const int tid = threadIdx.x;
  const int wave = tid >> 6, lane = tid & 63;
  const int m0 = blockIdx.y * BM, n0 = blockIdx.x * BN;
  const int wm = (wave >> 1) * 32, wn = (wave & 1) * 64;
  const int lrow = lane >> 2, lcol = (lane & 3) * 8;

  f32x4 acc[2][4] = {};

  for (int k0 = 0; k0 < E_; k0 += BK) {
#pragma unroll
    for (int c = wave; c < NCH; c += 4) {
      if (c < ACH)
        gload16(A + (size_t)(m0 + c * 16 + lrow) * E_ + k0 + lcol, As + c * 16 * BK);
      else
        gload16(Bt + (size_t)(n0 + (c - ACH) * 16 + lrow) * E_ + k0 + lcol,
                Bs + (c - ACH) * 16 * BK);
    }
    __syncthreads();
    bf16x8 af[2], bfr[4];
#pragma unroll
    for (int mi = 0; mi < 2; ++mi)
      af[mi] = *(const bf16x8*)&As[(wm + mi * 16 + (lane & 15)) * BK + 8 * (lane >> 4)];
#pragma unroll
    for (int ni = 0; ni < 4; ++ni)
      bfr[ni] = *(const bf16x8*)&Bs[(wn + ni * 16 + (lane & 15)) * BK + 8 * (lane >> 4)];
#pragma unroll
    for (int mi = 0; mi < 2; ++mi)
#pragma unroll
      for (int ni = 0; ni < 4; ++ni)
        acc[mi][ni] = mfma16(af[mi], bfr[ni], acc[mi][ni]);
    __syncthreads();
  }

#pragma unroll
  for (int mi = 0; mi < 2; ++mi)
#pragma unroll
    for (int ni = 0; ni < 4; ++ni)
#pragma unroll
      for (int r = 0; r < 4; ++r) {
        const int m = m0 + wm + mi * 16 + ((lane >> 4) << 2) + r;
        const int n = n0 + wn + ni * 16 + (lane & 15);
        outp[(size_t)m * E_ + n] = acc[mi][ni][r] + bias[n];
      }
}

// ---------------- causal flash attention (QBLK=128) -------------------------
// Qh,Kh: [B*H][S][D] bf16; Vt: [B*H][D][S] bf16; O: [B][S][E] bf16
// 128-row q-tile per block; each of 4 waves owns 32 rows (2 A-fragments).
// Per staged 64-row K/V tile a wave now runs 32 MFMA against the SAME 16
// ds_read_b128s + 1 barrier + 1 staging issue -> per-tile fixed costs and
// K/V global traffic halve vs QBLK=64. Masking applies to the last 2 KV
// tiles (global col > global row). Static-max softmax, deferred row-sum.
// Grid: 512 blocks (32 bh x 16 qt), snake big-first: CU pair (c, 511-c)
// sums to constant 34 iterations.

__device__ __forceinline__ void stage_kv(
    const u16* __restrict__ Kh_head, const u16* __restrict__ Vt_head,
    int kv0, u16* kb, u16* vb, int wq, int lane) {
#pragma unroll
  for (int i = 0; i < 2; ++i) {
    const int c = 2 * wq + i;
    gload16(Kh_head + (size_t)(kv0 + lane) * D_ + c * 8, kb + c * 512);
    gload16(Vt_head + (size_t)lane * S_ + kv0 + c * 8, vb + c * 512);
  }
}

__global__ __launch_bounds__(256, 2) void flash_attn(
    const u16* __restrict__ Qh, const u16* __restrict__ Kh,
    const u16* __restrict__ Vt, u16* __restrict__ O) {
  __shared__ alignas(16) u16 Kb[2][4096];   // [buf][chunk*512 + row*8]
  __shared__ alignas(16) u16 Vb[2][4096];
  __shared__ alignas(16) u16 Pl[4][32][72];

  // Snake big-first over 512 (bh, qt) jobs, qt descending.
  const int i = blockIdx.x;            // 0..511
  const int ch = i >> 8, p = i & 255;
  const int j = (ch << 8) + ((ch & 1) ? (255 - p) : p);
  const int qt = 15 - (j >> 5);
  const int bh = j & 31;

  const int tid = threadIdx.x;
  const int wq = tid >> 6, lane = tid & 63;
  u16* pw = &Pl[wq][0][0];

  const int q0 = qt * 128;
  const int b = bh >> 4, h = bh & 15;
  constexpr float SC = 0.125f * 1.4426950408889634f;  // 1/sqrt(64) * log2(e)
  const int fr = lane & 15, fc = lane >> 4;

  // Q fragments: wave owns local rows [wq*32, wq*32+32), two 16-row groups.
  bf16x8 qf[2][2];
#pragma unroll
  for (int f = 0; f < 2; ++f) {
    const u16* Qb = Qh + ((size_t)bh * S_ + q0 + wq * 32 + f * 16 + fr) * D_ + 8 * fc;
    qf[f][0] = *(const bf16x8*)Qb;
    qf[f][1] = *(const bf16x8*)(Qb + 32);
  }
  const u16* Kh_head = Kh + (size_t)bh * S_ * D_;
  const u16* Vt_head = Vt + (size_t)bh * D_ * S_;

  float lacc[2][4] = {};
  f32x4 oacc[2][4] = {};
  const int nt = 2 * qt + 2;

  stage_kv(Kh_head, Vt_head, 0, Kb[0], Vb[0], wq, lane);
  __syncthreads();

  int cur = 0;
  for (int t = 0; t < nt; ++t) {
    if (t + 1 < nt)
      stage_kv(Kh_head, Vt_head, (t + 1) * 64, Kb[cur ^ 1], Vb[cur ^ 1], wq, lane);

    const u16* kb = Kb[cur];
    const u16* vb = Vb[cur];

    f32x4 sacc[2][4] = {};
    __builtin_amdgcn_s_setprio(1);
#pragma unroll
    for (int ni = 0; ni < 4; ++ni) {
      const bf16x8 k0 = *(const bf16x8*)&kb[fc * 512 + (16 * ni + fr) * 8];
      const bf16x8 k1 = *(const bf16x8*)&kb[(fc + 4) * 512 + (16 * ni + fr) * 8];
#pragma unroll
      for (int f = 0; f < 2; ++f) {
        sacc[f][ni] = mfma16(qf[f][0], k0, sacc[f][ni]);
        sacc[f][ni] = mfma16(qf[f][1], k1, sacc[f][ni]);
      }
    }
    __builtin_amdgcn_s_setprio(0);

    const bool diag2 = (t >= nt - 2);
    const int kv0 = t * 64;
#pragma unroll
    for (int f = 0; f < 2; ++f)
#pragma unroll
      for (int r = 0; r < 4; ++r) {
        const int grow = q0 + wq * 32 + f * 16 + (fc << 2) + r;  // global q row
#pragma unroll
        for (int ni = 0; ni < 4; ++ni) {
          float pv;
          if (diag2 && (kv0 + 16 * ni + fr) > grow) {
            pv = 0.f;
          } else {
            pv = __builtin_amdgcn_exp2f(sacc[f][ni][r] * SC);
          }
          sacc[f][ni][r] = pv;
          lacc[f][r] += pv;
        }
      }

    // P: C-layout f32 -> LDS -> A-layout bf16 (per-wave private 32x72)
#pragma unroll
    for (int f = 0; f < 2; ++f)
#pragma unroll
      for (int ni = 0; ni < 4; ++ni)
#pragma unroll
        for (int r = 0; r < 4; ++r)
          pw[(f * 16 + (fc << 2) + r) * 72 + 16 * ni + fr] = f2bf(sacc[f][ni][r]);
    asm volatile("s_waitcnt lgkmcnt(0)" ::: "memory");
    bf16x8 pa[2][2];
#pragma unroll
    for (int f = 0; f < 2; ++f) {
      pa[f][0] = *(const bf16x8*)&pw[(f * 16 + fr) * 72 + 8 * fc];
      pa[f][1] = *(const bf16x8*)&pw[(f * 16 + fr) * 72 + 32 + 8 * fc];
    }

    __builtin_amdgcn_s_setprio(1);
#pragma unroll
    for (int nd = 0; nd < 4; ++nd) {
      const bf16x8 v0 = *(const bf16x8*)&vb[fc * 512 + (16 * nd + fr) * 8];
      const bf16x8 v1 = *(const bf16x8*)&vb[(fc + 4) * 512 + (16 * nd + fr) * 8];
#pragma unroll
      for (int f = 0; f < 2; ++f) {
        oacc[f][nd] = mfma16(pa[f][0], v0, oacc[f][nd]);
        oacc[f][nd] = mfma16(pa[f][1], v1, oacc[f][nd]);
      }
    }
    __builtin_amdgcn_s_setprio(0);

    __syncthreads();   // drains staging vmcnt + protects buffer swap
    cur ^= 1;
  }

  // Deferred row-sum reduction: once per q-tile.
  float linv[2][4];
#pragma unroll
  for (int f = 0; f < 2; ++f)
#pragma unroll
    for (int r = 0; r < 4; ++r) {
      float l = lacc[f][r];
      l += __shfl_xor(l, 1);
      l += __shfl_xor(l, 2);
      l += __shfl_xor(l, 4);
      l += __shfl_xor(l, 8);
      linv[f][r] = __builtin_amdgcn_rcpf(l);
    }

  // write O in [B,S,E] bf16 (feeds final GEMM as A matrix)
#pragma unroll
  for (int f = 0; f < 2; ++f)
#pragma unroll
    for (int nd = 0; nd < 4; ++nd)
#pragma unroll
      for (int r = 0; r < 4; ++r) {
        const int qr = q0 + wq * 32 + f * 16 + (fc << 2) + r;
        const int d = 16 * nd + fr;
        const float v = oacc[f][nd][r] * linv[f][r];
        O[((size_t)b * S_ + qr) * E_ + h * D_ + d] = f2bf(v);
      }
}

// ---------------------------------------------------------------------------
extern "C" void kernel_launch(void* const* d_in, const int* in_sizes, int n_in,
                              void* d_out, int out_size, void* d_ws, size_t ws_size,
                              hipStream_t stream) {
  const float* q  = (const float*)d_in[0];
  const float* k  = (const float*)d_in[1];
  const float* v  = (const float*)d_in[2];
  const float* Wq = (const float*)d_in[3];
  const float* Wk = (const float*)d_in[4];
  const float* Wv = (const float*)d_in[5];
  const float* Wo = (const float*)d_in[6];
  const float* bo = (const float*)d_in[7];

  const size_t nBSE = (size_t)M_ * E_;  // 4M elems
  const size_t nEE  = (size_t)E_ * E_;  // 1M elems
  u16* qb  = (u16*)d_ws;
  u16* kb  = qb + nBSE;
  u16* vb  = kb + nBSE;
  u16* Wqb = vb + nBSE;
  u16* Wkb = Wqb + nEE;
  u16* Wvb = Wkb + nEE;
  u16* Wob = Wvb + nEE;
  u16* Qh  = Wob + nEE;
  u16* Kh  = Qh + nBSE;
  u16* Vt  = qb;   // reuse qb (dead after Q projection)
  u16* Oa  = vb;   // reuse vb (dead after V projection)

  CvtArgs ca;
  ca.src[0] = q;  ca.dst[0] = qb;  ca.n[0] = (int)nBSE;
  ca.src[1] = k;  ca.dst[1] = kb;  ca.n[1] = (int)nBSE;
  ca.src[2] = v;  ca.dst[2] = vb;  ca.n[2] = (int)nBSE;
  ca.src[3] = Wq; ca.dst[3] = Wqb; ca.n[3] = (int)nEE;
  ca.src[4] = Wk; ca.dst[4] = Wkb; ca.n[4] = (int)nEE;
  ca.src[5] = Wv; ca.dst[5] = Wvb; ca.n[5] = (int)nEE;
  ca.src[6] = Wo; ca.dst[6] = Wob; ca.n[6] = (int)nEE;
  cvt_kernel<<<dim3(512, 7), 256, 0, stream>>>(ca);

  // Fused Q/K/V projections: 8 x 32 x 3 = 768 blocks = 3 blocks/CU
  qkv_gemm<<<dim3(E_ / 128, M_ / 128, 3), 256, 0, stream>>>(
      qb, kb, vb, Wqb, Wkb, Wvb, Qh, Kh, Vt);
  // 512 blocks: one 128-row q-tile each, snake big-first ordering
  flash_attn<<<dim3(512), 256, 0, stream>>>(Qh, Kh, Vt, Oa);
  // O-projection: BM=64 -> 8 x 64 = 512 blocks = 2 blocks/CU
  oproj_gemm<<<dim3(E_ / 128, M_ / 64), 256, 0, stream>>>(Oa, Wob, bo, (float*)d_out);
}

// Round 10
// 130.943 us; speedup vs baseline: 1.1653x; 1.1653x over previous
//
#include <hip/hip_runtime.h>

typedef unsigned short u16;
typedef __bf16 bf16x8 __attribute__((ext_vector_type(8)));
typedef float f32x4 __attribute__((ext_vector_type(4)));
typedef unsigned u32x4 __attribute__((ext_vector_type(4)));

#define B_ 2
#define S_ 2048
#define E_ 1024
#define H_ 16
#define D_ 64
#define M_ (B_ * S_)   // 4096

__device__ inline u16 f2bf(float f) {
  union { float f; unsigned int u; } c; c.f = f;
  unsigned int u = c.u;
  return (u16)((u + 0x7FFFu + ((u >> 16) & 1u)) >> 16);
}

__device__ inline f32x4 mfma16(bf16x8 a, bf16x8 b, f32x4 c) {
  return __builtin_amdgcn_mfma_f32_16x16x32_bf16(a, b, c, 0, 0, 0);
}

__device__ inline void gload16(const void* g, void* lds) {
  __builtin_amdgcn_global_load_lds(
      (const __attribute__((address_space(1))) unsigned int*)g,
      (__attribute__((address_space(3))) unsigned int*)lds, 16, 0, 0);
}

// ---------------- fp32 -> bf16 conversion (all 7 tensors, one launch) -------
struct CvtArgs {
  const float* src[7];
  u16* dst[7];
  int n[7];
};

__global__ __launch_bounds__(256) void cvt_kernel(CvtArgs a) {
  const int arr = blockIdx.y;
  const int n = a.n[arr];
  const float* __restrict__ s = a.src[arr];
  u16* __restrict__ d = a.dst[arr];
  const int stride = gridDim.x * blockDim.x;
  for (int i = blockIdx.x * blockDim.x + threadIdx.x; i * 4 < n; i += stride) {
    const float4 f = *(const float4*)(s + 4 * i);
    ushort4 o;
    o.x = f2bf(f.x); o.y = f2bf(f.y); o.z = f2bf(f.z); o.w = f2bf(f.w);
    *(ushort4*)(d + 4 * i) = o;
  }
}

// ---------------- fused QKV projection: 3 GEMMs in one launch ---------------
__global__ __launch_bounds__(256, 4) void qkv_gemm(
    const u16* __restrict__ qb, const u16* __restrict__ kb,
    const u16* __restrict__ vbp, const u16* __restrict__ Wqb,
    const u16* __restrict__ Wkb, const u16* __restrict__ Wvb,
    u16* __restrict__ Qh, u16* __restrict__ Kh, u16* __restrict__ Vt) {
  constexpr int BM = 128, BN = 128, BK = 32;
  __shared__ alignas(16) u16 As[BM * BK];
  __shared__ alignas(16) u16 Bs[BN * BK];
  const int z = blockIdx.z;
  const u16* A  = (z == 0) ? qb  : (z == 1) ? kb  : vbp;
  const u16* Bt = (z == 0) ? Wqb : (z == 1) ? Wkb : Wvb;
  u16* outp     = (z == 0) ? Qh  : (z == 1) ? Kh  : Vt;

  const int tid = threadIdx.x;
  const int wave = tid >> 6, lane = tid & 63;
  const int m0 = blockIdx.y * BM, n0 = blockIdx.x * BN;
  const int wm = (wave >> 1) * 64, wn = (wave & 1) * 64;
  const int lrow = lane >> 2, lcol = (lane & 3) * 8;

  f32x4 acc[4][4] = {};

  for (int k0 = 0; k0 < E_; k0 += BK) {
#pragma unroll
    for (int i = 0; i < 2; ++i) {
      const int chunk = wave * 2 + i;  // 0..7, 16 rows each
      const int row = chunk * 16 + lrow;
      gload16(A + (size_t)(m0 + row) * E_ + k0 + lcol, As + chunk * 16 * BK);
      gload16(Bt + (size_t)(n0 + row) * E_ + k0 + lcol, Bs + chunk * 16 * BK);
    }
    __syncthreads();
    bf16x8 af[4], bfr[4];
#pragma unroll
    for (int mi = 0; mi < 4; ++mi)
      af[mi] = *(const bf16x8*)&As[(wm + mi * 16 + (lane & 15)) * BK + 8 * (lane >> 4)];
#pragma unroll
    for (int ni = 0; ni < 4; ++ni)
      bfr[ni] = *(const bf16x8*)&Bs[(wn + ni * 16 + (lane & 15)) * BK + 8 * (lane >> 4)];
#pragma unroll
    for (int mi = 0; mi < 4; ++mi)
#pragma unroll
      for (int ni = 0; ni < 4; ++ni)
        acc[mi][ni] = mfma16(af[mi], bfr[ni], acc[mi][ni]);
    __syncthreads();
  }

#pragma unroll
  for (int mi = 0; mi < 4; ++mi)
#pragma unroll
    for (int ni = 0; ni < 4; ++ni)
#pragma unroll
      for (int r = 0; r < 4; ++r) {
        const int m = m0 + wm + mi * 16 + ((lane >> 4) << 2) + r;
        const int n = n0 + wn + ni * 16 + (lane & 15);
        const float v = acc[mi][ni][r];
        const int b = m >> 11, s = m & (S_ - 1), h = n >> 6, d = n & 63;
        if (z != 2) {
          outp[((((size_t)b * H_ + h) * S_ + s) << 6) + d] = f2bf(v);
        } else {
          outp[(((size_t)b * H_ + h) * D_ + d) * S_ + s] = f2bf(v);
        }
      }
}

// ---------------- output projection GEMM (BM=64 -> 512 blocks = 2/CU) ------
__global__ __launch_bounds__(256, 4) void oproj_gemm(
    const u16* __restrict__ A, const u16* __restrict__ Bt,
    const float* __restrict__ bias, float* __restrict__ outp) {
  constexpr int BM = 64, BN = 128, BK = 32;
  constexpr int ACH = BM / 16, NCH = ACH + BN / 16;  // 4 + 8 = 12
  __shared__ alignas(16) u16 As[BM * BK];
  __shared__ alignas(16) u16 Bs[BN * BK];
  const int tid = threadIdx.x;
  const int wave = tid >> 6, lane = tid & 63;
  const int m0 = blockIdx.y * BM, n0 = blockIdx.x * BN;
  const int wm = (wave >> 1) * 32, wn = (wave & 1) * 64;
  const int lrow = lane >> 2, lcol = (lane & 3) * 8;

  f32x4 acc[2][4] = {};

  for (int k0 = 0; k0 < E_; k0 += BK) {
#pragma unroll
    for (int c = wave; c < NCH; c += 4) {
      if (c < ACH)
        gload16(A + (size_t)(m0 + c * 16 + lrow) * E_ + k0 + lcol, As + c * 16 * BK);
      else
        gload16(Bt + (size_t)(n0 + (c - ACH) * 16 + lrow) * E_ + k0 + lcol,
                Bs + (c - ACH) * 16 * BK);
    }
    __syncthreads();
    bf16x8 af[2], bfr[4];
#pragma unroll
    for (int mi = 0; mi < 2; ++mi)
      af[mi] = *(const bf16x8*)&As[(wm + mi * 16 + (lane & 15)) * BK + 8 * (lane >> 4)];
#pragma unroll
    for (int ni = 0; ni < 4; ++ni)
      bfr[ni] = *(const bf16x8*)&Bs[(wn + ni * 16 + (lane & 15)) * BK + 8 * (lane >> 4)];
#pragma unroll
    for (int mi = 0; mi < 2; ++mi)
#pragma unroll
      for (int ni = 0; ni < 4; ++ni)
        acc[mi][ni] = mfma16(af[mi], bfr[ni], acc[mi][ni]);
    __syncthreads();
  }

#pragma unroll
  for (int mi = 0; mi < 2; ++mi)
#pragma unroll
    for (int ni = 0; ni < 4; ++ni)
#pragma unroll
      for (int r = 0; r < 4; ++r) {
        const int m = m0 + wm + mi * 16 + ((lane >> 4) << 2) + r;
        const int n = n0 + wn + ni * 16 + (lane & 15);
        outp[(size_t)m * E_ + n] = acc[mi][ni][r] + bias[n];
      }
}

// ---------------- causal flash attention (r7 grid + in-register P) ----------
// Qh,Kh: [B*H][S][D] bf16; Vt: [B*H][D][S] bf16; O: [B][S][E] bf16
// SWAPPED QK^T (mfma(K,Q)): lane (fr,fc) holds P[kv=16ni+4fc+r][q=fr] -- the
// q-row is lane-local, so P->PV-A-fragment needs only an fc-group exchange:
// 8 cvt_pk (VALU) + 4 permlane32_swap (VALU) + 4 shfl_xor16 + selects.
// This deletes the per-tile P LDS round-trip (16 ds_write_u16 + lgkmcnt(0)
// + 2 ds_read_b128) that made r7 LDS-pipe-bound, and frees the P buffer
// (LDS 41984->32768 -> 4 blocks/CU with the 1024-block grid).
// Static-max softmax, scalar per-lane row-sum, reduced once in epilogue.

__device__ __forceinline__ void stage_kv(
    const u16* __restrict__ Kh_head, const u16* __restrict__ Vt_head,
    int kv0, u16* kb, u16* vb, int wq, int lane) {
#pragma unroll
  for (int i = 0; i < 2; ++i) {
    const int c = 2 * wq + i;
    gload16(Kh_head + (size_t)(kv0 + lane) * D_ + c * 8, kb + c * 512);
    gload16(Vt_head + (size_t)lane * S_ + kv0 + c * 8, vb + c * 512);
  }
}

__global__ __launch_bounds__(256, 2) void flash_attn(
    const u16* __restrict__ Qh, const u16* __restrict__ Kh,
    const u16* __restrict__ Vt, u16* __restrict__ O) {
  __shared__ alignas(16) u16 Kb[2][4096];   // [buf][chunk*512 + row*8]
  __shared__ alignas(16) u16 Vb[2][4096];

  // Snake big-first over 1024 (bh, qt) jobs (r7 mapping).
  const int i = blockIdx.x;            // 0..1023
  const int ch = i >> 8, p = i & 255;
  const int j = (ch << 8) + ((ch & 1) ? (255 - p) : p);
  const int qt = 31 - (j >> 5);
  const int bh = j & 31;

  const int tid = threadIdx.x;
  const int wq = tid >> 6, lane = tid & 63;

  const int q0 = qt * 64;
  const int b = bh >> 4, h = bh & 15;
  constexpr float SC = 0.125f * 1.4426950408889634f;  // 1/sqrt(64) * log2(e)
  const int fr = lane & 15, fc = lane >> 4;

  const u16* Qbase = Qh + ((size_t)bh * S_ + q0 + wq * 16 + fr) * D_ + 8 * fc;
  const bf16x8 qf0 = *(const bf16x8*)Qbase;
  const bf16x8 qf1 = *(const bf16x8*)(Qbase + 32);
  const u16* Kh_head = Kh + (size_t)bh * S_ * D_;
  const u16* Vt_head = Vt + (size_t)bh * D_ * S_;

  float lacc = 0.f;          // per-lane partial row sum for q-row fr
  f32x4 oacc[4] = {};
  const int nt = qt + 1;

  stage_kv(Kh_head, Vt_head, 0, Kb[0], Vb[0], wq, lane);
  __syncthreads();

  int cur = 0;
  for (int t = 0; t < nt; ++t) {
    if (t + 1 < nt)
      stage_kv(Kh_head, Vt_head, (t + 1) * 64, Kb[cur ^ 1], Vb[cur ^ 1], wq, lane);

    const u16* kb = Kb[cur];
    const u16* vb = Vb[cur];

    // QK^T swapped: sacc[ni] rows = kv (16ni + 4fc + r), col = q-row fr
    f32x4 sacc[4] = {};
    __builtin_amdgcn_s_setprio(1);
#pragma unroll
    for (int ni = 0; ni < 4; ++ni) {
      const bf16x8 k0 = *(const bf16x8*)&kb[fc * 512 + (16 * ni + fr) * 8];
      const bf16x8 k1 = *(const bf16x8*)&kb[(fc + 4) * 512 + (16 * ni + fr) * 8];
      sacc[ni] = mfma16(k0, qf0, sacc[ni]);
      sacc[ni] = mfma16(k1, qf1, sacc[ni]);
    }
    __builtin_amdgcn_s_setprio(0);

    // mask + exp (static max); kv_local = 16ni+4fc+r, q_local = wq*16+fr
    const bool diag = (t == qt);
    const int qloc = wq * 16 + fr;
#pragma unroll
    for (int ni = 0; ni < 4; ++ni)
#pragma unroll
      for (int r = 0; r < 4; ++r) {
        const int kvloc = 16 * ni + 4 * fc + r;
        float pv;
        if (diag && kvloc > qloc) {
          pv = 0.f;
        } else {
          pv = __builtin_amdgcn_exp2f(sacc[ni][r] * SC);
        }
        sacc[ni][r] = pv;
        lacc += pv;
      }

    // pack P to bf16 pairs: w[ni][h] = pk(p[2h], p[2h+1]); pidx = 8ni+2fc+h
    unsigned w[4][2];
#pragma unroll
    for (int ni = 0; ni < 4; ++ni) {
      asm("v_cvt_pk_bf16_f32 %0, %1, %2"
          : "=v"(w[ni][0]) : "v"(sacc[ni][0]), "v"(sacc[ni][1]));
      asm("v_cvt_pk_bf16_f32 %0, %1, %2"
          : "=v"(w[ni][1]) : "v"(sacc[ni][2]), "v"(sacc[ni][3]));
    }

    // exchange: lane (fr,fc) needs pidx 4fc+c (pa0) and 16+4fc+c (pa1)
    unsigned paw0[4], paw1[4];
#pragma unroll
    for (int pair = 0; pair < 2; ++pair) {   // 0: (ni0,ni1)->pa0, 1: (ni2,ni3)->pa1
      unsigned xx[2], yy[2], tt[2];
#pragma unroll
      for (int hh = 0; hh < 2; ++hh) {
        unsigned a = w[2 * pair][hh], bb = w[2 * pair + 1][hh];
        asm volatile("v_permlane32_swap_b32 %0, %1" : "+v"(a), "+v"(bb));
        // a: g0=w0h@0 g1=w0h@1 g2=w1h@0 g3=w1h@1
        // bb: g0=w0h@2 g1=w0h@3 g2=w1h@2 g3=w1h@3
        xx[hh] = a; yy[hh] = bb;
        const unsigned s = (fc & 1) ? a : bb;
        tt[hh] = (unsigned)__shfl_xor((int)s, 16);
      }
      unsigned* pw_ = pair ? paw1 : paw0;
      pw_[0] = (fc & 1) ? tt[0] : xx[0];
      pw_[1] = (fc & 1) ? tt[1] : xx[1];
      pw_[2] = (fc & 1) ? yy[0] : tt[0];
      pw_[3] = (fc & 1) ? yy[1] : tt[1];
    }
    bf16x8 pa0, pa1;
    {
      u32x4 t0 = {paw0[0], paw0[1], paw0[2], paw0[3]};
      u32x4 t1 = {paw1[0], paw1[1], paw1[2], paw1[3]};
      __builtin_memcpy(&pa0, &t0, 16);
      __builtin_memcpy(&pa1, &t1, 16);
    }

    __builtin_amdgcn_s_setprio(1);
#pragma unroll
    for (int nd = 0; nd < 4; ++nd) {
      const bf16x8 v0 = *(const bf16x8*)&vb[fc * 512 + (16 * nd + fr) * 8];
      const bf16x8 v1 = *(const bf16x8*)&vb[(fc + 4) * 512 + (16 * nd + fr) * 8];
      oacc[nd] = mfma16(pa0, v0, oacc[nd]);
      oacc[nd] = mfma16(pa1, v1, oacc[nd]);
    }
    __builtin_amdgcn_s_setprio(0);

    __syncthreads();   // drains staging vmcnt + protects buffer swap
    cur ^= 1;
  }

  // epilogue row-sum: l[fr] = sum over fc groups; then gather l[4fc+r]
  float l = lacc;
  l += __shfl_xor(l, 16);
  l += __shfl_xor(l, 32);
  float linv[4];
#pragma unroll
  for (int r = 0; r < 4; ++r)
    linv[r] = __builtin_amdgcn_rcpf(__shfl(l, 4 * fc + r));

  // write O in [B,S,E] bf16 (O C-layout: q-row = (fc<<2)+r, d-col = fr)
#pragma unroll
  for (int nd = 0; nd < 4; ++nd) {
#pragma unroll
    for (int r = 0; r < 4; ++r) {
      const int qr = q0 + wq * 16 + (fc << 2) + r;
      const int d = 16 * nd + fr;
      const float v = oacc[nd][r] * linv[r];
      O[((size_t)b * S_ + qr) * E_ + h * D_ + d] = f2bf(v);
    }
  }
}

// ---------------------------------------------------------------------------
extern "C" void kernel_launch(void* const* d_in, const int* in_sizes, int n_in,
                              void* d_out, int out_size, void* d_ws, size_t ws_size,
                              hipStream_t stream) {
  const float* q  = (const float*)d_in[0];
  const float* k  = (const float*)d_in[1];
  const float* v  = (const float*)d_in[2];
  const float* Wq = (const float*)d_in[3];
  const float* Wk = (const float*)d_in[4];
  const float* Wv = (const float*)d_in[5];
  const float* Wo = (const float*)d_in[6];
  const float* bo = (const float*)d_in[7];

  const size_t nBSE = (size_t)M_ * E_;  // 4M elems
  const size_t nEE  = (size_t)E_ * E_;  // 1M elems
  u16* qb  = (u16*)d_ws;
  u16* kb  = qb + nBSE;
  u16* vb  = kb + nBSE;
  u16* Wqb = vb + nBSE;
  u16* Wkb = Wqb + nEE;
  u16* Wvb = Wkb + nEE;
  u16* Wob = Wvb + nEE;
  u16* Qh  = Wob + nEE;
  u16* Kh  = Qh + nBSE;
  u16* Vt  = qb;   // reuse qb (dead after Q projection)
  u16* Oa  = vb;   // reuse vb (dead after V projection)

  CvtArgs ca;
  ca.src[0] = q;  ca.dst[0] = qb;  ca.n[0] = (int)nBSE;
  ca.src[1] = k;  ca.dst[1] = kb;  ca.n[1] = (int)nBSE;
  ca.src[2] = v;  ca.dst[2] = vb;  ca.n[2] = (int)nBSE;
  ca.src[3] = Wq; ca.dst[3] = Wqb; ca.n[3] = (int)nEE;
  ca.src[4] = Wk; ca.dst[4] = Wkb; ca.n[4] = (int)nEE;
  ca.src[5] = Wv; ca.dst[5] = Wvb; ca.n[5] = (int)nEE;
  ca.src[6] = Wo; ca.dst[6] = Wob; ca.n[6] = (int)nEE;
  cvt_kernel<<<dim3(512, 7), 256, 0, stream>>>(ca);

  // Fused Q/K/V projections: 8 x 32 x 3 = 768 blocks = 3 blocks/CU
  qkv_gemm<<<dim3(E_ / 128, M_ / 128, 3), 256, 0, stream>>>(
      qb, kb, vb, Wqb, Wkb, Wvb, Qh, Kh, Vt);
  // 1024 blocks: one 64-row q-tile each, snake big-first ordering
  flash_attn<<<dim3(1024), 256, 0, stream>>>(Qh, Kh, Vt, Oa);
  // O-projection: BM=64 -> 8 x 64 = 512 blocks = 2 blocks/CU
  oproj_gemm<<<dim3(E_ / 128, M_ / 64), 256, 0, stream>>>(Oa, Wob, bo, (float*)d_out);
}

// Round 11
// 126.384 us; speedup vs baseline: 1.2073x; 1.0361x over previous
//
#include <hip/hip_runtime.h>

typedef unsigned short u16;
typedef __bf16 bf16x8 __attribute__((ext_vector_type(8)));
typedef float f32x4 __attribute__((ext_vector_type(4)));
typedef unsigned u32x4 __attribute__((ext_vector_type(4)));

#define B_ 2
#define S_ 2048
#define E_ 1024
#define H_ 16
#define D_ 64
#define M_ (B_ * S_)   // 4096

__device__ inline u16 f2bf(float f) {
  union { float f; unsigned int u; } c; c.f = f;
  unsigned int u = c.u;
  return (u16)((u + 0x7FFFu + ((u >> 16) & 1u)) >> 16);
}

__device__ inline f32x4 mfma16(bf16x8 a, bf16x8 b, f32x4 c) {
  return __builtin_amdgcn_mfma_f32_16x16x32_bf16(a, b, c, 0, 0, 0);
}

__device__ inline void gload16(const void* g, void* lds) {
  __builtin_amdgcn_global_load_lds(
      (const __attribute__((address_space(1))) unsigned int*)g,
      (__attribute__((address_space(3))) unsigned int*)lds, 16, 0, 0);
}

// ---------------- fp32 -> bf16 conversion (all 7 tensors, one launch) -------
struct CvtArgs {
  const float* src[7];
  u16* dst[7];
  int n[7];
};

__global__ __launch_bounds__(256) void cvt_kernel(CvtArgs a) {
  const int arr = blockIdx.y;
  const int n = a.n[arr];
  const float* __restrict__ s = a.src[arr];
  u16* __restrict__ d = a.dst[arr];
  const int stride = gridDim.x * blockDim.x;
  for (int i = blockIdx.x * blockDim.x + threadIdx.x; i * 4 < n; i += stride) {
    const float4 f = *(const float4*)(s + 4 * i);
    ushort4 o;
    o.x = f2bf(f.x); o.y = f2bf(f.y); o.z = f2bf(f.z); o.w = f2bf(f.w);
    *(ushort4*)(d + 4 * i) = o;
  }
}

// ---------------- fused QKV projection: 3 GEMMs in one launch ---------------
__global__ __launch_bounds__(256, 4) void qkv_gemm(
    const u16* __restrict__ qb, const u16* __restrict__ kb,
    const u16* __restrict__ vbp, const u16* __restrict__ Wqb,
    const u16* __restrict__ Wkb, const u16* __restrict__ Wvb,
    u16* __restrict__ Qh, u16* __restrict__ Kh, u16* __restrict__ Vt) {
  constexpr int BM = 128, BN = 128, BK = 32;
  __shared__ alignas(16) u16 As[BM * BK];
  __shared__ alignas(16) u16 Bs[BN * BK];
  const int z = blockIdx.z;
  const u16* A  = (z == 0) ? qb  : (z == 1) ? kb  : vbp;
  const u16* Bt = (z == 0) ? Wqb : (z == 1) ? Wkb : Wvb;
  u16* outp     = (z == 0) ? Qh  : (z == 1) ? Kh  : Vt;

  const int tid = threadIdx.x;
  const int wave = tid >> 6, lane = tid & 63;
  const int m0 = blockIdx.y * BM, n0 = blockIdx.x * BN;
  const int wm = (wave >> 1) * 64, wn = (wave & 1) * 64;
  const int lrow = lane >> 2, lcol = (lane & 3) * 8;

  f32x4 acc[4][4] = {};

  for (int k0 = 0; k0 < E_; k0 += BK) {
#pragma unroll
    for (int i = 0; i < 2; ++i) {
      const int chunk = wave * 2 + i;  // 0..7, 16 rows each
      const int row = chunk * 16 + lrow;
      gload16(A + (size_t)(m0 + row) * E_ + k0 + lcol, As + chunk * 16 * BK);
      gload16(Bt + (size_t)(n0 + row) * E_ + k0 + lcol, Bs + chunk * 16 * BK);
    }
    __syncthreads();
    bf16x8 af[4], bfr[4];
#pragma unroll
    for (int mi = 0; mi < 4; ++mi)
      af[mi] = *(const bf16x8*)&As[(wm + mi * 16 + (lane & 15)) * BK + 8 * (lane >> 4)];
#pragma unroll
    for (int ni = 0; ni < 4; ++ni)
      bfr[ni] = *(const bf16x8*)&Bs[(wn + ni * 16 + (lane & 15)) * BK + 8 * (lane >> 4)];
#pragma unroll
    for (int mi = 0; mi < 4; ++mi)
#pragma unroll
      for (int ni = 0; ni < 4; ++ni)
        acc[mi][ni] = mfma16(af[mi], bfr[ni], acc[mi][ni]);
    __syncthreads();
  }

#pragma unroll
  for (int mi = 0; mi < 4; ++mi)
#pragma unroll
    for (int ni = 0; ni < 4; ++ni)
#pragma unroll
      for (int r = 0; r < 4; ++r) {
        const int m = m0 + wm + mi * 16 + ((lane >> 4) << 2) + r;
        const int n = n0 + wn + ni * 16 + (lane & 15);
        const float v = acc[mi][ni][r];
        const int b = m >> 11, s = m & (S_ - 1), h = n >> 6, d = n & 63;
        if (z != 2) {
          outp[((((size_t)b * H_ + h) * S_ + s) << 6) + d] = f2bf(v);
        } else {
          outp[(((size_t)b * H_ + h) * D_ + d) * S_ + s] = f2bf(v);
        }
      }
}

// ---------------- output projection GEMM (BM=64 -> 512 blocks = 2/CU) ------
__global__ __launch_bounds__(256, 4) void oproj_gemm(
    const u16* __restrict__ A, const u16* __restrict__ Bt,
    const float* __restrict__ bias, float* __restrict__ outp) {
  constexpr int BM = 64, BN = 128, BK = 32;
  constexpr int ACH = BM / 16, NCH = ACH + BN / 16;  // 4 + 8 = 12
  __shared__ alignas(16) u16 As[BM * BK];
  __shared__ alignas(16) u16 Bs[BN * BK];
  const int tid = threadIdx.x;
  const int wave = tid >> 6, lane = tid & 63;
  const int m0 = blockIdx.y * BM, n0 = blockIdx.x * BN;
  const int wm = (wave >> 1) * 32, wn = (wave & 1) * 64;
  const int lrow = lane >> 2, lcol = (lane & 3) * 8;

  f32x4 acc[2][4] = {};

  for (int k0 = 0; k0 < E_; k0 += BK) {
#pragma unroll
    for (int c = wave; c < NCH; c += 4) {
      if (c < ACH)
        gload16(A + (size_t)(m0 + c * 16 + lrow) * E_ + k0 + lcol, As + c * 16 * BK);
      else
        gload16(Bt + (size_t)(n0 + (c - ACH) * 16 + lrow) * E_ + k0 + lcol,
                Bs + (c - ACH) * 16 * BK);
    }
    __syncthreads();
    bf16x8 af[2], bfr[4];
#pragma unroll
    for (int mi = 0; mi < 2; ++mi)
      af[mi] = *(const bf16x8*)&As[(wm + mi * 16 + (lane & 15)) * BK + 8 * (lane >> 4)];
#pragma unroll
    for (int ni = 0; ni < 4; ++ni)
      bfr[ni] = *(const bf16x8*)&Bs[(wn + ni * 16 + (lane & 15)) * BK + 8 * (lane >> 4)];
#pragma unroll
    for (int mi = 0; mi < 2; ++mi)
#pragma unroll
      for (int ni = 0; ni < 4; ++ni)
        acc[mi][ni] = mfma16(af[mi], bfr[ni], acc[mi][ni]);
    __syncthreads();
  }

#pragma unroll
  for (int mi = 0; mi < 2; ++mi)
#pragma unroll
    for (int ni = 0; ni < 4; ++ni)
#pragma unroll
      for (int r = 0; r < 4; ++r) {
        const int m = m0 + wm + mi * 16 + ((lane >> 4) << 2) + r;
        const int n = n0 + wn + ni * 16 + (lane & 15);
        outp[(size_t)m * E_ + n] = acc[mi][ni][r] + bias[n];
      }
}

// ---------------- causal flash attention (3-deep pipeline, counted vmcnt) ---
// Qh,Kh: [B*H][S][D] bf16; Vt: [B*H][D][S] bf16; O: [B][S][E] bf16
// T3/T4: triple-buffered K/V staging with RAW s_barrier + counted vmcnt(4) --
// never drains to 0 in the main loop, so tile t+1/t+2 loads stay in flight
// across barriers. Iter t: wait own 4 loads of tile t -> barrier (all waves'
// tile-t loads landed; all waves done reading buf being recycled) -> issue
// stage(t+2) -> compute(t). Prefetch distance = 2 compute phases >> latency.
// Swapped QK^T + cvt_pk/permlane in-register P (r10), static-max softmax.

__device__ __forceinline__ void stage_kv(
    const u16* __restrict__ Kh_head, const u16* __restrict__ Vt_head,
    int kv0, u16* kb, u16* vb, int wq, int lane) {
#pragma unroll
  for (int i = 0; i < 2; ++i) {
    const int c = 2 * wq + i;
    gload16(Kh_head + (size_t)(kv0 + lane) * D_ + c * 8, kb + c * 512);
    gload16(Vt_head + (size_t)lane * S_ + kv0 + c * 8, vb + c * 512);
  }
}

__global__ __launch_bounds__(256, 2) void flash_attn(
    const u16* __restrict__ Qh, const u16* __restrict__ Kh,
    const u16* __restrict__ Vt, u16* __restrict__ O) {
  __shared__ alignas(16) u16 Kb[3][4096];   // [buf][chunk*512 + row*8]
  __shared__ alignas(16) u16 Vb[3][4096];

  // Plain big-first (LPT) over 1024 (bh, qt) jobs: 3 blocks/CU resident,
  // remainder backfills dynamically onto small jobs.
  const int j = blockIdx.x;            // 0..1023
  const int qt = 31 - (j >> 5);
  const int bh = j & 31;

  const int tid = threadIdx.x;
  const int wq = tid >> 6, lane = tid & 63;

  const int q0 = qt * 64;
  const int b = bh >> 4, h = bh & 15;
  constexpr float SC = 0.125f * 1.4426950408889634f;  // 1/sqrt(64) * log2(e)
  const int fr = lane & 15, fc = lane >> 4;

  const u16* Qbase = Qh + ((size_t)bh * S_ + q0 + wq * 16 + fr) * D_ + 8 * fc;
  const bf16x8 qf0 = *(const bf16x8*)Qbase;
  const bf16x8 qf1 = *(const bf16x8*)(Qbase + 32);
  const u16* Kh_head = Kh + (size_t)bh * S_ * D_;
  const u16* Vt_head = Vt + (size_t)bh * D_ * S_;

  float lacc = 0.f;          // per-lane partial row sum for q-row fr
  f32x4 oacc[4] = {};
  const int nt = qt + 1;

  // buffer rotation via pointer swap (no runtime indexing -> stays in regs)
  u16 *kA = Kb[0], *kB = Kb[1], *kC = Kb[2];
  u16 *vA = Vb[0], *vB = Vb[1], *vC = Vb[2];

  stage_kv(Kh_head, Vt_head, 0, kA, vA, wq, lane);
  stage_kv(Kh_head, Vt_head, 64, kB, vB, wq, lane);  // tile 1 (mem-valid even if nt==1)

  for (int t = 0; t < nt; ++t) {
    // wait own tile-t loads (4 newest = tile t+1's stay in flight), then
    // cross-wave barrier: after it, ALL waves' tile-t loads have landed and
    // ALL waves finished compute(t-1) (so recycling buf C is safe).
    if (t + 1 < nt) {
      asm volatile("s_waitcnt vmcnt(4)" ::: "memory");
    } else {
      asm volatile("s_waitcnt vmcnt(0)" ::: "memory");
    }
    __builtin_amdgcn_s_barrier();
    __builtin_amdgcn_sched_barrier(0);

    if (t + 2 < nt)
      stage_kv(Kh_head, Vt_head, (t + 2) * 64, kC, vC, wq, lane);

    const u16* kb = kA;
    const u16* vb = vA;

    // QK^T swapped: sacc[ni] rows = kv (16ni + 4fc + r), col = q-row fr
    f32x4 sacc[4] = {};
    __builtin_amdgcn_s_setprio(1);
#pragma unroll
    for (int ni = 0; ni < 4; ++ni) {
      const bf16x8 k0 = *(const bf16x8*)&kb[fc * 512 + (16 * ni + fr) * 8];
      const bf16x8 k1 = *(const bf16x8*)&kb[(fc + 4) * 512 + (16 * ni + fr) * 8];
      sacc[ni] = mfma16(k0, qf0, sacc[ni]);
      sacc[ni] = mfma16(k1, qf1, sacc[ni]);
    }
    __builtin_amdgcn_s_setprio(0);

    // mask + exp (static max); kv_local = 16ni+4fc+r, q_local = wq*16+fr
    const bool diag = (t == qt);
    const int qloc = wq * 16 + fr;
#pragma unroll
    for (int ni = 0; ni < 4; ++ni)
#pragma unroll
      for (int r = 0; r < 4; ++r) {
        const int kvloc = 16 * ni + 4 * fc + r;
        float pv;
        if (diag && kvloc > qloc) {
          pv = 0.f;
        } else {
          pv = __builtin_amdgcn_exp2f(sacc[ni][r] * SC);
        }
        sacc[ni][r] = pv;
        lacc += pv;
      }

    // pack P to bf16 pairs: w[ni][h] = pk(p[2h], p[2h+1]); pidx = 8ni+2fc+h
    unsigned w[4][2];
#pragma unroll
    for (int ni = 0; ni < 4; ++ni) {
      asm("v_cvt_pk_bf16_f32 %0, %1, %2"
          : "=v"(w[ni][0]) : "v"(sacc[ni][0]), "v"(sacc[ni][1]));
      asm("v_cvt_pk_bf16_f32 %0, %1, %2"
          : "=v"(w[ni][1]) : "v"(sacc[ni][2]), "v"(sacc[ni][3]));
    }

    // exchange: lane (fr,fc) needs pidx 4fc+c (pa0) and 16+4fc+c (pa1)
    unsigned paw0[4], paw1[4];
#pragma unroll
    for (int pair = 0; pair < 2; ++pair) {   // 0: (ni0,ni1)->pa0, 1: (ni2,ni3)->pa1
      unsigned xx[2], yy[2], tt[2];
#pragma unroll
      for (int hh = 0; hh < 2; ++hh) {
        unsigned a = w[2 * pair][hh], bb = w[2 * pair + 1][hh];
        asm volatile("v_permlane32_swap_b32 %0, %1" : "+v"(a), "+v"(bb));
        xx[hh] = a; yy[hh] = bb;
        const unsigned s = (fc & 1) ? a : bb;
        tt[hh] = (unsigned)__shfl_xor((int)s, 16);
      }
      unsigned* pw_ = pair ? paw1 : paw0;
      pw_[0] = (fc & 1) ? tt[0] : xx[0];
      pw_[1] = (fc & 1) ? tt[1] : xx[1];
      pw_[2] = (fc & 1) ? yy[0] : tt[0];
      pw_[3] = (fc & 1) ? yy[1] : tt[1];
    }
    bf16x8 pa0, pa1;
    {
      u32x4 t0 = {paw0[0], paw0[1], paw0[2], paw0[3]};
      u32x4 t1 = {paw1[0], paw1[1], paw1[2], paw1[3]};
      __builtin_memcpy(&pa0, &t0, 16);
      __builtin_memcpy(&pa1, &t1, 16);
    }

    __builtin_amdgcn_s_setprio(1);
#pragma unroll
    for (int nd = 0; nd < 4; ++nd) {
      const bf16x8 v0 = *(const bf16x8*)&vb[fc * 512 + (16 * nd + fr) * 8];
      const bf16x8 v1 = *(const bf16x8*)&vb[(fc + 4) * 512 + (16 * nd + fr) * 8];
      oacc[nd] = mfma16(pa0, v0, oacc[nd]);
      oacc[nd] = mfma16(pa1, v1, oacc[nd]);
    }
    __builtin_amdgcn_s_setprio(0);

    // rotate buffers: A <- B <- C <- A
    u16* tk = kA; kA = kB; kB = kC; kC = tk;
    u16* tv = vA; vA = vB; vB = vC; vC = tv;
  }

  // epilogue row-sum: l[fr] = sum over fc groups; then gather l[4fc+r]
  float l = lacc;
  l += __shfl_xor(l, 16);
  l += __shfl_xor(l, 32);
  float linv[4];
#pragma unroll
  for (int r = 0; r < 4; ++r)
    linv[r] = __builtin_amdgcn_rcpf(__shfl(l, 4 * fc + r));

  // write O in [B,S,E] bf16 (O C-layout: q-row = (fc<<2)+r, d-col = fr)
#pragma unroll
  for (int nd = 0; nd < 4; ++nd) {
#pragma unroll
    for (int r = 0; r < 4; ++r) {
      const int qr = q0 + wq * 16 + (fc << 2) + r;
      const int d = 16 * nd + fr;
      const float v = oacc[nd][r] * linv[r];
      O[((size_t)b * S_ + qr) * E_ + h * D_ + d] = f2bf(v);
    }
  }
}

// ---------------------------------------------------------------------------
extern "C" void kernel_launch(void* const* d_in, const int* in_sizes, int n_in,
                              void* d_out, int out_size, void* d_ws, size_t ws_size,
                              hipStream_t stream) {
  const float* q  = (const float*)d_in[0];
  const float* k  = (const float*)d_in[1];
  const float* v  = (const float*)d_in[2];
  const float* Wq = (const float*)d_in[3];
  const float* Wk = (const float*)d_in[4];
  const float* Wv = (const float*)d_in[5];
  const float* Wo = (const float*)d_in[6];
  const float* bo = (const float*)d_in[7];

  const size_t nBSE = (size_t)M_ * E_;  // 4M elems
  const size_t nEE  = (size_t)E_ * E_;  // 1M elems
  u16* qb  = (u16*)d_ws;
  u16* kb  = qb + nBSE;
  u16* vb  = kb + nBSE;
  u16* Wqb = vb + nBSE;
  u16* Wkb = Wqb + nEE;
  u16* Wvb = Wkb + nEE;
  u16* Wob = Wvb + nEE;
  u16* Qh  = Wob + nEE;
  u16* Kh  = Qh + nBSE;
  u16* Vt  = qb;   // reuse qb (dead after Q projection)
  u16* Oa  = vb;   // reuse vb (dead after V projection)

  CvtArgs ca;
  ca.src[0] = q;  ca.dst[0] = qb;  ca.n[0] = (int)nBSE;
  ca.src[1] = k;  ca.dst[1] = kb;  ca.n[1] = (int)nBSE;
  ca.src[2] = v;  ca.dst[2] = vb;  ca.n[2] = (int)nBSE;
  ca.src[3] = Wq; ca.dst[3] = Wqb; ca.n[3] = (int)nEE;
  ca.src[4] = Wk; ca.dst[4] = Wkb; ca.n[4] = (int)nEE;
  ca.src[5] = Wv; ca.dst[5] = Wvb; ca.n[5] = (int)nEE;
  ca.src[6] = Wo; ca.dst[6] = Wob; ca.n[6] = (int)nEE;
  cvt_kernel<<<dim3(512, 7), 256, 0, stream>>>(ca);

  // Fused Q/K/V projections: 8 x 32 x 3 = 768 blocks = 3 blocks/CU
  qkv_gemm<<<dim3(E_ / 128, M_ / 128, 3), 256, 0, stream>>>(
      qb, kb, vb, Wqb, Wkb, Wvb, Qh, Kh, Vt);
  // 1024 blocks: one 64-row q-tile each, big-first (LPT) ordering
  flash_attn<<<dim3(1024), 256, 0, stream>>>(Qh, Kh, Vt, Oa);
  // O-projection: BM=64 -> 8 x 64 = 512 blocks = 2 blocks/CU
  oproj_gemm<<<dim3(E_ / 128, M_ / 64), 256, 0, stream>>>(Oa, Wob, bo, (float*)d_out);
}

// Round 12
// 122.168 us; speedup vs baseline: 1.2490x; 1.0345x over previous
//
#include <hip/hip_runtime.h>

typedef unsigned short u16;
typedef __bf16 bf16x8 __attribute__((ext_vector_type(8)));
typedef float f32x4 __attribute__((ext_vector_type(4)));
typedef unsigned u32x4 __attribute__((ext_vector_type(4)));

#define B_ 2
#define S_ 2048
#define E_ 1024
#define H_ 16
#define D_ 64
#define M_ (B_ * S_)   // 4096

__device__ inline u16 f2bf(float f) {
  union { float f; unsigned int u; } c; c.f = f;
  unsigned int u = c.u;
  return (u16)((u + 0x7FFFu + ((u >> 16) & 1u)) >> 16);
}

__device__ inline f32x4 mfma16(bf16x8 a, bf16x8 b, f32x4 c) {
  return __builtin_amdgcn_mfma_f32_16x16x32_bf16(a, b, c, 0, 0, 0);
}

__device__ inline void gload16(const void* g, void* lds) {
  __builtin_amdgcn_global_load_lds(
      (const __attribute__((address_space(1))) unsigned int*)g,
      (__attribute__((address_space(3))) unsigned int*)lds, 16, 0, 0);
}

// ---------------- fp32 -> bf16 conversion (all 7 tensors, one launch) -------
struct CvtArgs {
  const float* src[7];
  u16* dst[7];
  int n[7];
};

__global__ __launch_bounds__(256) void cvt_kernel(CvtArgs a) {
  const int arr = blockIdx.y;
  const int n = a.n[arr];
  const float* __restrict__ s = a.src[arr];
  u16* __restrict__ d = a.dst[arr];
  const int stride = gridDim.x * blockDim.x;
  for (int i = blockIdx.x * blockDim.x + threadIdx.x; i * 4 < n; i += stride) {
    const float4 f = *(const float4*)(s + 4 * i);
    ushort4 o;
    o.x = f2bf(f.x); o.y = f2bf(f.y); o.z = f2bf(f.z); o.w = f2bf(f.w);
    *(ushort4*)(d + 4 * i) = o;
  }
}

// ---------------- fused QKV projection: pipelined + swizzled ----------------
// T3/T4: triple-buffered As/Bs, raw s_barrier + counted vmcnt(4) -- never
// drains to 0 in the main loop (mirror of the flash r11 structure).
// T2: both-sides XOR swizzle -- stage source col-chunk ^= ((lrow>>1)&3),
// fragment read slot = fc ^ ((fr>>1)&3) -> 2 rows/bank-quad = conflict-free.
// XCD-bucketed 1-D grid: wg&7 = xcd owns m-panels {4xcd..4xcd+3} for all n,z
// -> per-XCD L2 set = A 1MB + B 2MB <= 4MB.
__global__ __launch_bounds__(256, 3) void qkv_gemm(
    const u16* __restrict__ qb, const u16* __restrict__ kb,
    const u16* __restrict__ vbp, const u16* __restrict__ Wqb,
    const u16* __restrict__ Wkb, const u16* __restrict__ Wvb,
    u16* __restrict__ Qh, u16* __restrict__ Kh, u16* __restrict__ Vt) {
  constexpr int BM = 128, BN = 128, BK = 32;
  __shared__ alignas(16) u16 As[3][BM * BK];
  __shared__ alignas(16) u16 Bs[3][BN * BK];

  // decode: xcd-bucketed mapping over 768 jobs
  const int wg = blockIdx.x;           // 0..767
  const int xcd = wg & 7, idx = wg >> 3;
  const int nb = idx & 7, mz = idx >> 3;   // nb: n-block, mz: 0..11
  const int z = mz >> 2;
  const int m0 = (xcd * 4 + (mz & 3)) * BM, n0 = nb * BN;

  const u16* A  = (z == 0) ? qb  : (z == 1) ? kb  : vbp;
  const u16* Bt = (z == 0) ? Wqb : (z == 1) ? Wkb : Wvb;
  u16* outp     = (z == 0) ? Qh  : (z == 1) ? Kh  : Vt;

  const int tid = threadIdx.x;
  const int wave = tid >> 6, lane = tid & 63;
  const int wm = (wave >> 1) * 64, wn = (wave & 1) * 64;
  const int fr = lane & 15, fc = lane >> 4;
  const int lrow = lane >> 2;
  const int lcol_sw = (((lane & 3) ^ ((lrow >> 1) & 3)) * 8);  // swizzled src

  f32x4 acc[4][4] = {};

  u16 *aA = As[0], *aB = As[1], *aC = As[2];
  u16 *bA = Bs[0], *bB = Bs[1], *bC = Bs[2];

  auto stage = [&](int k0, u16* as, u16* bs) {
#pragma unroll
    for (int i = 0; i < 2; ++i) {
      const int chunk = wave * 2 + i;  // 0..7, 16 rows each
      const int row = chunk * 16 + lrow;
      gload16(A + (size_t)(m0 + row) * E_ + k0 + lcol_sw, as + chunk * 16 * BK);
      gload16(Bt + (size_t)(n0 + row) * E_ + k0 + lcol_sw, bs + chunk * 16 * BK);
    }
  };

  constexpr int NK = E_ / BK;  // 32
  stage(0, aA, bA);
  stage(BK, aB, bB);

  const int sl = (fc ^ ((fr >> 1) & 3)) * 8;  // swizzled read slot (u16 units)

  for (int t = 0; t < NK; ++t) {
    if (t + 1 < NK) {
      asm volatile("s_waitcnt vmcnt(4)" ::: "memory");
    } else {
      asm volatile("s_waitcnt vmcnt(0)" ::: "memory");
    }
    __builtin_amdgcn_s_barrier();
    __builtin_amdgcn_sched_barrier(0);

    if (t + 2 < NK) stage((t + 2) * BK, aC, bC);

    bf16x8 af[4], bfr[4];
#pragma unroll
    for (int mi = 0; mi < 4; ++mi)
      af[mi] = *(const bf16x8*)&aA[(wm + mi * 16 + fr) * BK + sl];
#pragma unroll
    for (int ni = 0; ni < 4; ++ni)
      bfr[ni] = *(const bf16x8*)&bA[(wn + ni * 16 + fr) * BK + sl];
    __builtin_amdgcn_s_setprio(1);
#pragma unroll
    for (int mi = 0; mi < 4; ++mi)
#pragma unroll
      for (int ni = 0; ni < 4; ++ni)
        acc[mi][ni] = mfma16(af[mi], bfr[ni], acc[mi][ni]);
    __builtin_amdgcn_s_setprio(0);

    u16* tp;
    tp = aA; aA = aB; aB = aC; aC = tp;
    tp = bA; bA = bB; bB = bC; bC = tp;
  }

#pragma unroll
  for (int mi = 0; mi < 4; ++mi)
#pragma unroll
    for (int ni = 0; ni < 4; ++ni)
#pragma unroll
      for (int r = 0; r < 4; ++r) {
        const int m = m0 + wm + mi * 16 + (fc << 2) + r;
        const int n = n0 + wn + ni * 16 + fr;
        const float v = acc[mi][ni][r];
        const int b = m >> 11, s = m & (S_ - 1), h = n >> 6, d = n & 63;
        if (z != 2) {
          outp[((((size_t)b * H_ + h) * S_ + s) << 6) + d] = f2bf(v);
        } else {
          outp[(((size_t)b * H_ + h) * D_ + d) * S_ + s] = f2bf(v);
        }
      }
}

// ---------------- output projection GEMM (BM=64 -> 512 blocks = 2/CU) ------
__global__ __launch_bounds__(256, 4) void oproj_gemm(
    const u16* __restrict__ A, const u16* __restrict__ Bt,
    const float* __restrict__ bias, float* __restrict__ outp) {
  constexpr int BM = 64, BN = 128, BK = 32;
  constexpr int ACH = BM / 16, NCH = ACH + BN / 16;  // 4 + 8 = 12
  __shared__ alignas(16) u16 As[BM * BK];
  __shared__ alignas(16) u16 Bs[BN * BK];
  const int tid = threadIdx.x;
  const int wave = tid >> 6, lane = tid & 63;
  const int m0 = blockIdx.y * BM, n0 = blockIdx.x * BN;
  const int wm = (wave >> 1) * 32, wn = (wave & 1) * 64;
  const int lrow = lane >> 2, lcol = (lane & 3) * 8;

  f32x4 acc[2][4] = {};

  for (int k0 = 0; k0 < E_; k0 += BK) {
#pragma unroll
    for (int c = wave; c < NCH; c += 4) {
      if (c < ACH)
        gload16(A + (size_t)(m0 + c * 16 + lrow) * E_ + k0 + lcol, As + c * 16 * BK);
      else
        gload16(Bt + (size_t)(n0 + (c - ACH) * 16 + lrow) * E_ + k0 + lcol,
                Bs + (c - ACH) * 16 * BK);
    }
    __syncthreads();
    bf16x8 af[2], bfr[4];
#pragma unroll
    for (int mi = 0; mi < 2; ++mi)
      af[mi] = *(const bf16x8*)&As[(wm + mi * 16 + (lane & 15)) * BK + 8 * (lane >> 4)];
#pragma unroll
    for (int ni = 0; ni < 4; ++ni)
      bfr[ni] = *(const bf16x8*)&Bs[(wn + ni * 16 + (lane & 15)) * BK + 8 * (lane >> 4)];
#pragma unroll
    for (int mi = 0; mi < 2; ++mi)
#pragma unroll
      for (int ni = 0; ni < 4; ++ni)
        acc[mi][ni] = mfma16(af[mi], bfr[ni], acc[mi][ni]);
    __syncthreads();
  }

#pragma unroll
  for (int mi = 0; mi < 2; ++mi)
#pragma unroll
    for (int ni = 0; ni < 4; ++ni)
#pragma unroll
      for (int r = 0; r < 4; ++r) {
        const int m = m0 + wm + mi * 16 + ((lane >> 4) << 2) + r;
        const int n = n0 + wn + ni * 16 + (lane & 15);
        outp[(size_t)m * E_ + n] = acc[mi][ni][r] + bias[n];
      }
}

// ---------------- causal flash attention (r11: 3-deep pipeline) -------------
__device__ __forceinline__ void stage_kv(
    const u16* __restrict__ Kh_head, const u16* __restrict__ Vt_head,
    int kv0, u16* kb, u16* vb, int wq, int lane) {
#pragma unroll
  for (int i = 0; i < 2; ++i) {
    const int c = 2 * wq + i;
    gload16(Kh_head + (size_t)(kv0 + lane) * D_ + c * 8, kb + c * 512);
    gload16(Vt_head + (size_t)lane * S_ + kv0 + c * 8, vb + c * 512);
  }
}

__global__ __launch_bounds__(256, 2) void flash_attn(
    const u16* __restrict__ Qh, const u16* __restrict__ Kh,
    const u16* __restrict__ Vt, u16* __restrict__ O) {
  __shared__ alignas(16) u16 Kb[3][4096];   // [buf][chunk*512 + row*8]
  __shared__ alignas(16) u16 Vb[3][4096];

  const int j = blockIdx.x;            // 0..1023, big-first (LPT)
  const int qt = 31 - (j >> 5);
  const int bh = j & 31;

  const int tid = threadIdx.x;
  const int wq = tid >> 6, lane = tid & 63;

  const int q0 = qt * 64;
  const int b = bh >> 4, h = bh & 15;
  constexpr float SC = 0.125f * 1.4426950408889634f;  // 1/sqrt(64) * log2(e)
  const int fr = lane & 15, fc = lane >> 4;

  const u16* Qbase = Qh + ((size_t)bh * S_ + q0 + wq * 16 + fr) * D_ + 8 * fc;
  const bf16x8 qf0 = *(const bf16x8*)Qbase;
  const bf16x8 qf1 = *(const bf16x8*)(Qbase + 32);
  const u16* Kh_head = Kh + (size_t)bh * S_ * D_;
  const u16* Vt_head = Vt + (size_t)bh * D_ * S_;

  float lacc = 0.f;          // per-lane partial row sum for q-row fr
  f32x4 oacc[4] = {};
  const int nt = qt + 1;

  u16 *kA = Kb[0], *kB = Kb[1], *kC = Kb[2];
  u16 *vA = Vb[0], *vB = Vb[1], *vC = Vb[2];

  stage_kv(Kh_head, Vt_head, 0, kA, vA, wq, lane);
  stage_kv(Kh_head, Vt_head, 64, kB, vB, wq, lane);

  for (int t = 0; t < nt; ++t) {
    if (t + 1 < nt) {
      asm volatile("s_waitcnt vmcnt(4)" ::: "memory");
    } else {
      asm volatile("s_waitcnt vmcnt(0)" ::: "memory");
    }
    __builtin_amdgcn_s_barrier();
    __builtin_amdgcn_sched_barrier(0);

    if (t + 2 < nt)
      stage_kv(Kh_head, Vt_head, (t + 2) * 64, kC, vC, wq, lane);

    const u16* kb = kA;
    const u16* vb = vA;

    // QK^T swapped: sacc[ni] rows = kv (16ni + 4fc + r), col = q-row fr
    f32x4 sacc[4] = {};
    __builtin_amdgcn_s_setprio(1);
#pragma unroll
    for (int ni = 0; ni < 4; ++ni) {
      const bf16x8 k0 = *(const bf16x8*)&kb[fc * 512 + (16 * ni + fr) * 8];
      const bf16x8 k1 = *(const bf16x8*)&kb[(fc + 4) * 512 + (16 * ni + fr) * 8];
      sacc[ni] = mfma16(k0, qf0, sacc[ni]);
      sacc[ni] = mfma16(k1, qf1, sacc[ni]);
    }
    __builtin_amdgcn_s_setprio(0);

    const bool diag = (t == qt);
    const int qloc = wq * 16 + fr;
#pragma unroll
    for (int ni = 0; ni < 4; ++ni)
#pragma unroll
      for (int r = 0; r < 4; ++r) {
        const int kvloc = 16 * ni + 4 * fc + r;
        float pv;
        if (diag && kvloc > qloc) {
          pv = 0.f;
        } else {
          pv = __builtin_amdgcn_exp2f(sacc[ni][r] * SC);
        }
        sacc[ni][r] = pv;
        lacc += pv;
      }

    unsigned w[4][2];
#pragma unroll
    for (int ni = 0; ni < 4; ++ni) {
      asm("v_cvt_pk_bf16_f32 %0, %1, %2"
          : "=v"(w[ni][0]) : "v"(sacc[ni][0]), "v"(sacc[ni][1]));
      asm("v_cvt_pk_bf16_f32 %0, %1, %2"
          : "=v"(w[ni][1]) : "v"(sacc[ni][2]), "v"(sacc[ni][3]));
    }

    unsigned paw0[4], paw1[4];
#pragma unroll
    for (int pair = 0; pair < 2; ++pair) {
      unsigned xx[2], yy[2], tt[2];
#pragma unroll
      for (int hh = 0; hh < 2; ++hh) {
        unsigned a = w[2 * pair][hh], bb = w[2 * pair + 1][hh];
        asm volatile("v_permlane32_swap_b32 %0, %1" : "+v"(a), "+v"(bb));
        xx[hh] = a; yy[hh] = bb;
        const unsigned s = (fc & 1) ? a : bb;
        tt[hh] = (unsigned)__shfl_xor((int)s, 16);
      }
      unsigned* pw_ = pair ? paw1 : paw0;
      pw_[0] = (fc & 1) ? tt[0] : xx[0];
      pw_[1] = (fc & 1) ? tt[1] : xx[1];
      pw_[2] = (fc & 1) ? yy[0] : tt[0];
      pw_[3] = (fc & 1) ? yy[1] : tt[1];
    }
    bf16x8 pa0, pa1;
    {
      u32x4 t0 = {paw0[0], paw0[1], paw0[2], paw0[3]};
      u32x4 t1 = {paw1[0], paw1[1], paw1[2], paw1[3]};
      __builtin_memcpy(&pa0, &t0, 16);
      __builtin_memcpy(&pa1, &t1, 16);
    }

    __builtin_amdgcn_s_setprio(1);
#pragma unroll
    for (int nd = 0; nd < 4; ++nd) {
      const bf16x8 v0 = *(const bf16x8*)&vb[fc * 512 + (16 * nd + fr) * 8];
      const bf16x8 v1 = *(const bf16x8*)&vb[(fc + 4) * 512 + (16 * nd + fr) * 8];
      oacc[nd] = mfma16(pa0, v0, oacc[nd]);
      oacc[nd] = mfma16(pa1, v1, oacc[nd]);
    }
    __builtin_amdgcn_s_setprio(0);

    u16* tk = kA; kA = kB; kB = kC; kC = tk;
    u16* tv = vA; vA = vB; vB = vC; vC = tv;
  }

  float l = lacc;
  l += __shfl_xor(l, 16);
  l += __shfl_xor(l, 32);
  float linv[4];
#pragma unroll
  for (int r = 0; r < 4; ++r)
    linv[r] = __builtin_amdgcn_rcpf(__shfl(l, 4 * fc + r));

#pragma unroll
  for (int nd = 0; nd < 4; ++nd) {
#pragma unroll
    for (int r = 0; r < 4; ++r) {
      const int qr = q0 + wq * 16 + (fc << 2) + r;
      const int d = 16 * nd + fr;
      const float v = oacc[nd][r] * linv[r];
      O[((size_t)b * S_ + qr) * E_ + h * D_ + d] = f2bf(v);
    }
  }
}

// ---------------------------------------------------------------------------
extern "C" void kernel_launch(void* const* d_in, const int* in_sizes, int n_in,
                              void* d_out, int out_size, void* d_ws, size_t ws_size,
                              hipStream_t stream) {
  const float* q  = (const float*)d_in[0];
  const float* k  = (const float*)d_in[1];
  const float* v  = (const float*)d_in[2];
  const float* Wq = (const float*)d_in[3];
  const float* Wk = (const float*)d_in[4];
  const float* Wv = (const float*)d_in[5];
  const float* Wo = (const float*)d_in[6];
  const float* bo = (const float*)d_in[7];

  const size_t nBSE = (size_t)M_ * E_;  // 4M elems
  const size_t nEE  = (size_t)E_ * E_;  // 1M elems
  u16* qb  = (u16*)d_ws;
  u16* kb  = qb + nBSE;
  u16* vb  = kb + nBSE;
  u16* Wqb = vb + nBSE;
  u16* Wkb = Wqb + nEE;
  u16* Wvb = Wkb + nEE;
  u16* Wob = Wvb + nEE;
  u16* Qh  = Wob + nEE;
  u16* Kh  = Qh + nBSE;
  u16* Vt  = qb;   // reuse qb (dead after Q projection)
  u16* Oa  = vb;   // reuse vb (dead after V projection)

  CvtArgs ca;
  ca.src[0] = q;  ca.dst[0] = qb;  ca.n[0] = (int)nBSE;
  ca.src[1] = k;  ca.dst[1] = kb;  ca.n[1] = (int)nBSE;
  ca.src[2] = v;  ca.dst[2] = vb;  ca.n[2] = (int)nBSE;
  ca.src[3] = Wq; ca.dst[3] = Wqb; ca.n[3] = (int)nEE;
  ca.src[4] = Wk; ca.dst[4] = Wkb; ca.n[4] = (int)nEE;
  ca.src[5] = Wv; ca.dst[5] = Wvb; ca.n[5] = (int)nEE;
  ca.src[6] = Wo; ca.dst[6] = Wob; ca.n[6] = (int)nEE;
  cvt_kernel<<<dim3(512, 7), 256, 0, stream>>>(ca);

  // Fused Q/K/V projections: 768 blocks, xcd-bucketed 1-D mapping
  qkv_gemm<<<dim3(768), 256, 0, stream>>>(
      qb, kb, vb, Wqb, Wkb, Wvb, Qh, Kh, Vt);
  // 1024 blocks: one 64-row q-tile each, big-first (LPT) ordering
  flash_attn<<<dim3(1024), 256, 0, stream>>>(Qh, Kh, Vt, Oa);
  // O-projection: BM=64 -> 8 x 64 = 512 blocks = 2 blocks/CU
  oproj_gemm<<<dim3(E_ / 128, M_ / 64), 256, 0, stream>>>(Oa, Wob, bo, (float*)d_out);
}

// Round 13
// 115.522 us; speedup vs baseline: 1.3208x; 1.0575x over previous
//
#include <hip/hip_runtime.h>

typedef unsigned short u16;
typedef __bf16 bf16x8 __attribute__((ext_vector_type(8)));
typedef float f32x4 __attribute__((ext_vector_type(4)));
typedef unsigned u32x4 __attribute__((ext_vector_type(4)));

#define B_ 2
#define S_ 2048
#define E_ 1024
#define H_ 16
#define D_ 64
#define M_ (B_ * S_)   // 4096

__device__ inline u16 f2bf(float f) {
  union { float f; unsigned int u; } c; c.f = f;
  unsigned int u = c.u;
  return (u16)((u + 0x7FFFu + ((u >> 16) & 1u)) >> 16);
}

__device__ inline f32x4 mfma16(bf16x8 a, bf16x8 b, f32x4 c) {
  return __builtin_amdgcn_mfma_f32_16x16x32_bf16(a, b, c, 0, 0, 0);
}

__device__ inline void gload16(const void* g, void* lds) {
  __builtin_amdgcn_global_load_lds(
      (const __attribute__((address_space(1))) unsigned int*)g,
      (__attribute__((address_space(3))) unsigned int*)lds, 16, 0, 0);
}

// ---------------- fp32 -> bf16 conversion (all 7 tensors, one launch) -------
struct CvtArgs {
  const float* src[7];
  u16* dst[7];
  int n[7];
};

__global__ __launch_bounds__(256) void cvt_kernel(CvtArgs a) {
  const int arr = blockIdx.y;
  const int n = a.n[arr];
  const float* __restrict__ s = a.src[arr];
  u16* __restrict__ d = a.dst[arr];
  const int stride = gridDim.x * blockDim.x;
  for (int i = blockIdx.x * blockDim.x + threadIdx.x; i * 4 < n; i += stride) {
    const float4 f = *(const float4*)(s + 4 * i);
    ushort4 o;
    o.x = f2bf(f.x); o.y = f2bf(f.y); o.z = f2bf(f.z); o.w = f2bf(f.w);
    *(ushort4*)(d + 4 * i) = o;
  }
}

// ---------------- fused QKV projection (r12: pipelined + swizzled) ----------
__global__ __launch_bounds__(256, 3) void qkv_gemm(
    const u16* __restrict__ qb, const u16* __restrict__ kb,
    const u16* __restrict__ vbp, const u16* __restrict__ Wqb,
    const u16* __restrict__ Wkb, const u16* __restrict__ Wvb,
    u16* __restrict__ Qh, u16* __restrict__ Kh, u16* __restrict__ Vt) {
  constexpr int BM = 128, BN = 128, BK = 32;
  __shared__ alignas(16) u16 As[3][BM * BK];
  __shared__ alignas(16) u16 Bs[3][BN * BK];

  const int wg = blockIdx.x;           // 0..767, xcd-bucketed
  const int xcd = wg & 7, idx = wg >> 3;
  const int nb = idx & 7, mz = idx >> 3;
  const int z = mz >> 2;
  const int m0 = (xcd * 4 + (mz & 3)) * BM, n0 = nb * BN;

  const u16* A  = (z == 0) ? qb  : (z == 1) ? kb  : vbp;
  const u16* Bt = (z == 0) ? Wqb : (z == 1) ? Wkb : Wvb;
  u16* outp     = (z == 0) ? Qh  : (z == 1) ? Kh  : Vt;

  const int tid = threadIdx.x;
  const int wave = tid >> 6, lane = tid & 63;
  const int wm = (wave >> 1) * 64, wn = (wave & 1) * 64;
  const int fr = lane & 15, fc = lane >> 4;
  const int lrow = lane >> 2;
  const int lcol_sw = (((lane & 3) ^ ((lrow >> 1) & 3)) * 8);  // swizzled src

  f32x4 acc[4][4] = {};

  u16 *aA = As[0], *aB = As[1], *aC = As[2];
  u16 *bA = Bs[0], *bB = Bs[1], *bC = Bs[2];

  auto stage = [&](int k0, u16* as, u16* bs) {
#pragma unroll
    for (int i = 0; i < 2; ++i) {
      const int chunk = wave * 2 + i;
      const int row = chunk * 16 + lrow;
      gload16(A + (size_t)(m0 + row) * E_ + k0 + lcol_sw, as + chunk * 16 * BK);
      gload16(Bt + (size_t)(n0 + row) * E_ + k0 + lcol_sw, bs + chunk * 16 * BK);
    }
  };

  constexpr int NK = E_ / BK;  // 32
  stage(0, aA, bA);
  stage(BK, aB, bB);

  const int sl = (fc ^ ((fr >> 1) & 3)) * 8;  // swizzled read slot

  for (int t = 0; t < NK; ++t) {
    if (t + 1 < NK) {
      asm volatile("s_waitcnt vmcnt(4)" ::: "memory");
    } else {
      asm volatile("s_waitcnt vmcnt(0)" ::: "memory");
    }
    __builtin_amdgcn_s_barrier();
    __builtin_amdgcn_sched_barrier(0);

    if (t + 2 < NK) stage((t + 2) * BK, aC, bC);

    bf16x8 af[4], bfr[4];
#pragma unroll
    for (int mi = 0; mi < 4; ++mi)
      af[mi] = *(const bf16x8*)&aA[(wm + mi * 16 + fr) * BK + sl];
#pragma unroll
    for (int ni = 0; ni < 4; ++ni)
      bfr[ni] = *(const bf16x8*)&bA[(wn + ni * 16 + fr) * BK + sl];
    __builtin_amdgcn_s_setprio(1);
#pragma unroll
    for (int mi = 0; mi < 4; ++mi)
#pragma unroll
      for (int ni = 0; ni < 4; ++ni)
        acc[mi][ni] = mfma16(af[mi], bfr[ni], acc[mi][ni]);
    __builtin_amdgcn_s_setprio(0);

    u16* tp;
    tp = aA; aA = aB; aB = aC; aC = tp;
    tp = bA; bA = bB; bB = bC; bC = tp;
  }

#pragma unroll
  for (int mi = 0; mi < 4; ++mi)
#pragma unroll
    for (int ni = 0; ni < 4; ++ni)
#pragma unroll
      for (int r = 0; r < 4; ++r) {
        const int m = m0 + wm + mi * 16 + (fc << 2) + r;
        const int n = n0 + wn + ni * 16 + fr;
        const float v = acc[mi][ni][r];
        const int b = m >> 11, s = m & (S_ - 1), h = n >> 6, d = n & 63;
        if (z != 2) {
          outp[((((size_t)b * H_ + h) * S_ + s) << 6) + d] = f2bf(v);
        } else {
          outp[(((size_t)b * H_ + h) * D_ + d) * S_ + s] = f2bf(v);
        }
      }
}

// ---------------- output projection GEMM (pipelined + swizzled, BM=64) -----
__global__ __launch_bounds__(256, 4) void oproj_gemm(
    const u16* __restrict__ A, const u16* __restrict__ Bt,
    const float* __restrict__ bias, float* __restrict__ outp) {
  constexpr int BM = 64, BN = 128, BK = 32;
  __shared__ alignas(16) u16 As[3][BM * BK];   // 4KB per buf
  __shared__ alignas(16) u16 Bs[3][BN * BK];   // 8KB per buf -> 36KB total

  // xcd-bucketed: xcd owns 8 m-panels; per-XCD set = A 1MB + B 2MB <= L2
  const int wg = blockIdx.x;           // 0..511
  const int xcd = wg & 7, idx = wg >> 3;
  const int nb = idx & 7, mi_ = idx >> 3;  // 0..7
  const int m0 = (xcd * 8 + mi_) * BM, n0 = nb * BN;

  const int tid = threadIdx.x;
  const int wave = tid >> 6, lane = tid & 63;
  const int wm = (wave >> 1) * 32, wn = (wave & 1) * 64;
  const int fr = lane & 15, fc = lane >> 4;
  const int lrow = lane >> 2;
  const int lcol_sw = (((lane & 3) ^ ((lrow >> 1) & 3)) * 8);

  f32x4 acc[2][4] = {};

  u16 *aA = As[0], *aB = As[1], *aC = As[2];
  u16 *bA = Bs[0], *bB = Bs[1], *bC = Bs[2];

  auto stage = [&](int k0, u16* as, u16* bs) {
#pragma unroll
    for (int i = 0; i < 3; ++i) {
      const int c = wave + 4 * i;   // 0..11: 4 A-chunks then 8 B-chunks
      if (c < 4)
        gload16(A + (size_t)(m0 + c * 16 + lrow) * E_ + k0 + lcol_sw, as + c * 16 * BK);
      else
        gload16(Bt + (size_t)(n0 + (c - 4) * 16 + lrow) * E_ + k0 + lcol_sw,
                bs + (c - 4) * 16 * BK);
    }
  };

  constexpr int NK = E_ / BK;  // 32
  stage(0, aA, bA);
  stage(BK, aB, bB);

  const int sl = (fc ^ ((fr >> 1) & 3)) * 8;

  for (int t = 0; t < NK; ++t) {
    if (t + 1 < NK) {
      asm volatile("s_waitcnt vmcnt(3)" ::: "memory");
    } else {
      asm volatile("s_waitcnt vmcnt(0)" ::: "memory");
    }
    __builtin_amdgcn_s_barrier();
    __builtin_amdgcn_sched_barrier(0);

    if (t + 2 < NK) stage((t + 2) * BK, aC, bC);

    bf16x8 af[2], bfr[4];
#pragma unroll
    for (int mi = 0; mi < 2; ++mi)
      af[mi] = *(const bf16x8*)&aA[(wm + mi * 16 + fr) * BK + sl];
#pragma unroll
    for (int ni = 0; ni < 4; ++ni)
      bfr[ni] = *(const bf16x8*)&bA[(wn + ni * 16 + fr) * BK + sl];
    __builtin_amdgcn_s_setprio(1);
#pragma unroll
    for (int mi = 0; mi < 2; ++mi)
#pragma unroll
      for (int ni = 0; ni < 4; ++ni)
        acc[mi][ni] = mfma16(af[mi], bfr[ni], acc[mi][ni]);
    __builtin_amdgcn_s_setprio(0);

    u16* tp;
    tp = aA; aA = aB; aB = aC; aC = tp;
    tp = bA; bA = bB; bB = bC; bC = tp;
  }

#pragma unroll
  for (int mi = 0; mi < 2; ++mi)
#pragma unroll
    for (int ni = 0; ni < 4; ++ni)
#pragma unroll
      for (int r = 0; r < 4; ++r) {
        const int m = m0 + wm + mi * 16 + (fc << 2) + r;
        const int n = n0 + wn + ni * 16 + fr;
        outp[(size_t)m * E_ + n] = acc[mi][ni][r] + bias[n];
      }
}

// ---------------- causal flash attention (8-wave QBLK=128, 3-deep pipe) -----
// 512 blocks x 512 threads; each of 8 waves owns 16 q-rows (per-wave code
// identical to r11). 2 blocks/CU at 48KB LDS -> 4 waves/SIMD. Per-wave
// staging: 1 K-chunk + 1 V-chunk -> counted vmcnt(2). Mask on last 2 KV
// tiles via global-index compare. Snake pairing (i, 511-i): per-CU resident
// pair sums to a constant 34 iterations.

__device__ __forceinline__ void stage_kv8(
    const u16* __restrict__ Kh_head, const u16* __restrict__ Vt_head,
    int kv0, u16* kb, u16* vb, int wq, int lane) {
  gload16(Kh_head + (size_t)(kv0 + lane) * D_ + wq * 8, kb + wq * 512);
  gload16(Vt_head + (size_t)lane * S_ + kv0 + wq * 8, vb + wq * 512);
}

__global__ __launch_bounds__(512, 4) void flash_attn(
    const u16* __restrict__ Qh, const u16* __restrict__ Kh,
    const u16* __restrict__ Vt, u16* __restrict__ O) {
  __shared__ alignas(16) u16 Kb[3][4096];   // [buf][chunk*512 + row*8]
  __shared__ alignas(16) u16 Vb[3][4096];

  // snake pairing over 512 jobs: blocks i and 511-i sum to 34 iters
  const int i = blockIdx.x;            // 0..511
  const int ch = i >> 8, p = i & 255;
  const int j = (ch << 8) + ((ch & 1) ? (255 - p) : p);
  const int qt = 15 - (j >> 5);        // 128-row q-tile, big-first
  const int bh = j & 31;

  const int tid = threadIdx.x;
  const int wq = tid >> 6, lane = tid & 63;

  const int q0 = qt * 128;
  const int b = bh >> 4, h = bh & 15;
  constexpr float SC = 0.125f * 1.4426950408889634f;  // 1/sqrt(64) * log2(e)
  const int fr = lane & 15, fc = lane >> 4;

  const u16* Qbase = Qh + ((size_t)bh * S_ + q0 + wq * 16 + fr) * D_ + 8 * fc;
  const bf16x8 qf0 = *(const bf16x8*)Qbase;
  const bf16x8 qf1 = *(const bf16x8*)(Qbase + 32);
  const u16* Kh_head = Kh + (size_t)bh * S_ * D_;
  const u16* Vt_head = Vt + (size_t)bh * D_ * S_;

  float lacc = 0.f;          // per-lane partial row sum for q-row fr
  f32x4 oacc[4] = {};
  const int nt = 2 * qt + 2;

  u16 *kA = Kb[0], *kB = Kb[1], *kC = Kb[2];
  u16 *vA = Vb[0], *vB = Vb[1], *vC = Vb[2];

  stage_kv8(Kh_head, Vt_head, 0, kA, vA, wq, lane);
  stage_kv8(Kh_head, Vt_head, 64, kB, vB, wq, lane);

  for (int t = 0; t < nt; ++t) {
    if (t + 1 < nt) {
      asm volatile("s_waitcnt vmcnt(2)" ::: "memory");
    } else {
      asm volatile("s_waitcnt vmcnt(0)" ::: "memory");
    }
    __builtin_amdgcn_s_barrier();
    __builtin_amdgcn_sched_barrier(0);

    if (t + 2 < nt)
      stage_kv8(Kh_head, Vt_head, (t + 2) * 64, kC, vC, wq, lane);

    const u16* kb = kA;
    const u16* vb = vA;

    // QK^T swapped: sacc[ni] rows = kv (16ni + 4fc + r), col = q-row fr
    f32x4 sacc[4] = {};
    __builtin_amdgcn_s_setprio(1);
#pragma unroll
    for (int ni = 0; ni < 4; ++ni) {
      const bf16x8 k0 = *(const bf16x8*)&kb[fc * 512 + (16 * ni + fr) * 8];
      const bf16x8 k1 = *(const bf16x8*)&kb[(fc + 4) * 512 + (16 * ni + fr) * 8];
      sacc[ni] = mfma16(k0, qf0, sacc[ni]);
      sacc[ni] = mfma16(k1, qf1, sacc[ni]);
    }
    __builtin_amdgcn_s_setprio(0);

    // mask + exp (static max); global compare on the last two tiles
    const bool diag = (t >= nt - 2);
    const int qg = q0 + wq * 16 + fr;
    const int kvb = t * 64;
#pragma unroll
    for (int ni = 0; ni < 4; ++ni)
#pragma unroll
      for (int r = 0; r < 4; ++r) {
        const int kvg = kvb + 16 * ni + 4 * fc + r;
        float pv;
        if (diag && kvg > qg) {
          pv = 0.f;
        } else {
          pv = __builtin_amdgcn_exp2f(sacc[ni][r] * SC);
        }
        sacc[ni][r] = pv;
        lacc += pv;
      }

    unsigned w[4][2];
#pragma unroll
    for (int ni = 0; ni < 4; ++ni) {
      asm("v_cvt_pk_bf16_f32 %0, %1, %2"
          : "=v"(w[ni][0]) : "v"(sacc[ni][0]), "v"(sacc[ni][1]));
      asm("v_cvt_pk_bf16_f32 %0, %1, %2"
          : "=v"(w[ni][1]) : "v"(sacc[ni][2]), "v"(sacc[ni][3]));
    }

    unsigned paw0[4], paw1[4];
#pragma unroll
    for (int pair = 0; pair < 2; ++pair) {
      unsigned xx[2], yy[2], tt[2];
#pragma unroll
      for (int hh = 0; hh < 2; ++hh) {
        unsigned a = w[2 * pair][hh], bb = w[2 * pair + 1][hh];
        asm volatile("v_permlane32_swap_b32 %0, %1" : "+v"(a), "+v"(bb));
        xx[hh] = a; yy[hh] = bb;
        const unsigned s = (fc & 1) ? a : bb;
        tt[hh] = (unsigned)__shfl_xor((int)s, 16);
      }
      unsigned* pw_ = pair ? paw1 : paw0;
      pw_[0] = (fc & 1) ? tt[0] : xx[0];
      pw_[1] = (fc & 1) ? tt[1] : xx[1];
      pw_[2] = (fc & 1) ? yy[0] : tt[0];
      pw_[3] = (fc & 1) ? yy[1] : tt[1];
    }
    bf16x8 pa0, pa1;
    {
      u32x4 t0 = {paw0[0], paw0[1], paw0[2], paw0[3]};
      u32x4 t1 = {paw1[0], paw1[1], paw1[2], paw1[3]};
      __builtin_memcpy(&pa0, &t0, 16);
      __builtin_memcpy(&pa1, &t1, 16);
    }

    __builtin_amdgcn_s_setprio(1);
#pragma unroll
    for (int nd = 0; nd < 4; ++nd) {
      const bf16x8 v0 = *(const bf16x8*)&vb[fc * 512 + (16 * nd + fr) * 8];
      const bf16x8 v1 = *(const bf16x8*)&vb[(fc + 4) * 512 + (16 * nd + fr) * 8];
      oacc[nd] = mfma16(pa0, v0, oacc[nd]);
      oacc[nd] = mfma16(pa1, v1, oacc[nd]);
    }
    __builtin_amdgcn_s_setprio(0);

    u16* tk = kA; kA = kB; kB = kC; kC = tk;
    u16* tv = vA; vA = vB; vB = vC; vC = tv;
  }

  float l = lacc;
  l += __shfl_xor(l, 16);
  l += __shfl_xor(l, 32);
  float linv[4];
#pragma unroll
  for (int r = 0; r < 4; ++r)
    linv[r] = __builtin_amdgcn_rcpf(__shfl(l, 4 * fc + r));

#pragma unroll
  for (int nd = 0; nd < 4; ++nd) {
#pragma unroll
    for (int r = 0; r < 4; ++r) {
      const int qr = q0 + wq * 16 + (fc << 2) + r;
      const int d = 16 * nd + fr;
      const float v = oacc[nd][r] * linv[r];
      O[((size_t)b * S_ + qr) * E_ + h * D_ + d] = f2bf(v);
    }
  }
}

// ---------------------------------------------------------------------------
extern "C" void kernel_launch(void* const* d_in, const int* in_sizes, int n_in,
                              void* d_out, int out_size, void* d_ws, size_t ws_size,
                              hipStream_t stream) {
  const float* q  = (const float*)d_in[0];
  const float* k  = (const float*)d_in[1];
  const float* v  = (const float*)d_in[2];
  const float* Wq = (const float*)d_in[3];
  const float* Wk = (const float*)d_in[4];
  const float* Wv = (const float*)d_in[5];
  const float* Wo = (const float*)d_in[6];
  const float* bo = (const float*)d_in[7];

  const size_t nBSE = (size_t)M_ * E_;  // 4M elems
  const size_t nEE  = (size_t)E_ * E_;  // 1M elems
  u16* qb  = (u16*)d_ws;
  u16* kb  = qb + nBSE;
  u16* vb  = kb + nBSE;
  u16* Wqb = vb + nBSE;
  u16* Wkb = Wqb + nEE;
  u16* Wvb = Wkb + nEE;
  u16* Wob = Wvb + nEE;
  u16* Qh  = Wob + nEE;
  u16* Kh  = Qh + nBSE;
  u16* Vt  = qb;   // reuse qb (dead after Q projection)
  u16* Oa  = vb;   // reuse vb (dead after V projection)

  CvtArgs ca;
  ca.src[0] = q;  ca.dst[0] = qb;  ca.n[0] = (int)nBSE;
  ca.src[1] = k;  ca.dst[1] = kb;  ca.n[1] = (int)nBSE;
  ca.src[2] = v;  ca.dst[2] = vb;  ca.n[2] = (int)nBSE;
  ca.src[3] = Wq; ca.dst[3] = Wqb; ca.n[3] = (int)nEE;
  ca.src[4] = Wk; ca.dst[4] = Wkb; ca.n[4] = (int)nEE;
  ca.src[5] = Wv; ca.dst[5] = Wvb; ca.n[5] = (int)nEE;
  ca.src[6] = Wo; ca.dst[6] = Wob; ca.n[6] = (int)nEE;
  cvt_kernel<<<dim3(512, 7), 256, 0, stream>>>(ca);

  // Fused Q/K/V projections: 768 blocks, xcd-bucketed 1-D mapping
  qkv_gemm<<<dim3(768), 256, 0, stream>>>(
      qb, kb, vb, Wqb, Wkb, Wvb, Qh, Kh, Vt);
  // 512 blocks x 512 threads: one 128-row q-tile each, snake pairing
  flash_attn<<<dim3(512), 512, 0, stream>>>(Qh, Kh, Vt, Oa);
  // O-projection: 512 blocks, xcd-bucketed, pipelined
  oproj_gemm<<<dim3(512), 256, 0, stream>>>(Oa, Wob, bo, (float*)d_out);
}

// Round 15
// 111.490 us; speedup vs baseline: 1.3686x; 1.0362x over previous
//
#include <hip/hip_runtime.h>

typedef unsigned short u16;
typedef __bf16 bf16x8 __attribute__((ext_vector_type(8)));
typedef float f32x4 __attribute__((ext_vector_type(4)));
typedef unsigned u32x4 __attribute__((ext_vector_type(4)));

#define B_ 2
#define S_ 2048
#define E_ 1024
#define H_ 16
#define D_ 64
#define M_ (B_ * S_)   // 4096

__device__ inline u16 f2bf(float f) {
  union { float f; unsigned int u; } c; c.f = f;
  unsigned int u = c.u;
  return (u16)((u + 0x7FFFu + ((u >> 16) & 1u)) >> 16);
}

__device__ inline f32x4 mfma16(bf16x8 a, bf16x8 b, f32x4 c) {
  return __builtin_amdgcn_mfma_f32_16x16x32_bf16(a, b, c, 0, 0, 0);
}

__device__ inline void gload16(const void* g, void* lds) {
  __builtin_amdgcn_global_load_lds(
      (const __attribute__((address_space(1))) unsigned int*)g,
      (__attribute__((address_space(3))) unsigned int*)lds, 16, 0, 0);
}

// ---------------- fp32 -> bf16 conversion (weights only now) ----------------
struct CvtArgs {
  const float* src[4];
  u16* dst[4];
  int n[4];
};

__global__ __launch_bounds__(256) void cvt_kernel(CvtArgs a) {
  const int arr = blockIdx.y;
  const int n = a.n[arr];
  const float* __restrict__ s = a.src[arr];
  u16* __restrict__ d = a.dst[arr];
  const int stride = gridDim.x * blockDim.x;
  for (int i = blockIdx.x * blockDim.x + threadIdx.x; i * 4 < n; i += stride) {
    const float4 f = *(const float4*)(s + 4 * i);
    ushort4 o;
    o.x = f2bf(f.x); o.y = f2bf(f.y); o.z = f2bf(f.z); o.w = f2bf(f.w);
    *(ushort4*)(d + 4 * i) = o;
  }
}

// ---------------- fused QKV projection: fp32-A fused convert + pipeline -----
// A (q/k/v) read directly as fp32, converted in-flight (float4 -> 2x
// v_cvt_pk_bf16_f32 -> ds_write_b64, write-side swizzle matches read side).
// Counted-vmcnt 3-deep pipeline; per iter vmcnt(2) certifies tile-t's B
// gload_lds AND tile-(t+1)'s A reg-loads. A(t+1) ALWAYS writes to current aB
// (the buffer that becomes aA after one rotation) -- r14's aC was the bug.
__global__ __launch_bounds__(256, 3) void qkv_gemm(
    const float* __restrict__ qf, const float* __restrict__ kf,
    const float* __restrict__ vf, const u16* __restrict__ Wqb,
    const u16* __restrict__ Wkb, const u16* __restrict__ Wvb,
    u16* __restrict__ Qh, u16* __restrict__ Kh, u16* __restrict__ Vt) {
  constexpr int BM = 128, BN = 128, BK = 32;
  __shared__ alignas(16) u16 As[3][BM * BK];
  __shared__ alignas(16) u16 Bs[3][BN * BK];

  const int wg = blockIdx.x;           // 0..767, xcd-bucketed
  const int xcd = wg & 7, idx = wg >> 3;
  const int nb = idx & 7, mz = idx >> 3;
  const int z = mz >> 2;
  const int m0 = (xcd * 4 + (mz & 3)) * BM, n0 = nb * BN;

  const float* A = (z == 0) ? qf  : (z == 1) ? kf  : vf;
  const u16* Bt  = (z == 0) ? Wqb : (z == 1) ? Wkb : Wvb;
  u16* outp      = (z == 0) ? Qh  : (z == 1) ? Kh  : Vt;

  const int tid = threadIdx.x;
  const int wave = tid >> 6, lane = tid & 63;
  const int wm = (wave >> 1) * 64, wn = (wave & 1) * 64;
  const int fr = lane & 15, fc = lane >> 4;
  const int lrow = lane >> 2;
  const int lcol_sw = (((lane & 3) ^ ((lrow >> 1) & 3)) * 8);  // B src swizzle

  // A fp32 addressing: per chunk ci, sub i2: row = (wave*2+ci)*16+i2*8+(lane>>3)
  const int arow_sub = lane >> 3;          // 0..7
  const int acol = (lane & 7) * 4;         // float col
  const int a_chunkbase = wave * 2;

  f32x4 acc[4][4] = {};

  u16 *aA = As[0], *aB = As[1], *aC = As[2];
  u16 *bA = Bs[0], *bB = Bs[1], *bC = Bs[2];

  float4 areg[4];   // held A data (tile t+1)

  auto loadA = [&](int k0) {
#pragma unroll
    for (int ci = 0; ci < 2; ++ci)
#pragma unroll
      for (int i2 = 0; i2 < 2; ++i2) {
        const int row = (a_chunkbase + ci) * 16 + i2 * 8 + arow_sub;
        areg[ci * 2 + i2] = *(const float4*)(A + (size_t)(m0 + row) * E_ + k0 + acol);
      }
  };
  auto writeA = [&](u16* as) {
#pragma unroll
    for (int ci = 0; ci < 2; ++ci)
#pragma unroll
      for (int i2 = 0; i2 < 2; ++i2) {
        const int rowLoc = i2 * 8 + arow_sub;
        const int row = (a_chunkbase + ci) * 16 + rowLoc;
        const float4 f = areg[ci * 2 + i2];
        unsigned d0, d1;
        asm("v_cvt_pk_bf16_f32 %0, %1, %2" : "=v"(d0) : "v"(f.x), "v"(f.y));
        asm("v_cvt_pk_bf16_f32 %0, %1, %2" : "=v"(d1) : "v"(f.z), "v"(f.w));
        const int slot = (acol >> 3) ^ ((rowLoc >> 1) & 3);
        const int half = (acol >> 2) & 1;
        *(uint2*)(&as[row * 32 + slot * 8 + half * 4]) = make_uint2(d0, d1);
      }
  };
  auto loadB = [&](int k0, u16* bs) {
#pragma unroll
    for (int i = 0; i < 2; ++i) {
      const int chunk = wave * 2 + i;
      const int row = chunk * 16 + lrow;
      gload16(Bt + (size_t)(n0 + row) * E_ + k0 + lcol_sw, bs + chunk * 16 * BK);
    }
  };

  constexpr int NK = E_ / BK;  // 32
  // Prologue: A(0)+B(0); write A(0); A(1)+B(1)
  loadA(0);
  loadB(0, bA);
  asm volatile("s_waitcnt vmcnt(2)" ::: "memory");  // A(0) regs ready
  writeA(aA);
  loadA(BK);
  loadB(BK, bB);

  const int sl = (fc ^ ((fr >> 1) & 3)) * 8;  // swizzled read slot

  for (int t = 0; t < NK; ++t) {
    if (t + 1 < NK) {
      asm volatile("s_waitcnt vmcnt(2)" ::: "memory");  // A(t+1) regs + B(t) LDS
      writeA(aB);  // A(t+1) -> buffer that becomes aA after one rotation
    } else {
      asm volatile("s_waitcnt vmcnt(0)" ::: "memory");
    }
    asm volatile("s_waitcnt lgkmcnt(0)" ::: "memory");
    __builtin_amdgcn_s_barrier();
    __builtin_amdgcn_sched_barrier(0);

    if (t + 2 < NK) {
      loadA((t + 2) * BK);
      loadB((t + 2) * BK, bC);
    }
    __builtin_amdgcn_sched_barrier(0);

    bf16x8 af[4], bfr[4];
#pragma unroll
    for (int mi = 0; mi < 4; ++mi)
      af[mi] = *(const bf16x8*)&aA[(wm + mi * 16 + fr) * BK + sl];
#pragma unroll
    for (int ni = 0; ni < 4; ++ni)
      bfr[ni] = *(const bf16x8*)&bA[(wn + ni * 16 + fr) * BK + sl];
    __builtin_amdgcn_s_setprio(1);
#pragma unroll
    for (int mi = 0; mi < 4; ++mi)
#pragma unroll
      for (int ni = 0; ni < 4; ++ni)
        acc[mi][ni] = mfma16(af[mi], bfr[ni], acc[mi][ni]);
    __builtin_amdgcn_s_setprio(0);

    u16* tp;
    tp = aA; aA = aB; aB = aC; aC = tp;
    tp = bA; bA = bB; bB = bC; bC = tp;
  }

#pragma unroll
  for (int mi = 0; mi < 4; ++mi)
#pragma unroll
    for (int ni = 0; ni < 4; ++ni)
#pragma unroll
      for (int r = 0; r < 4; ++r) {
        const int m = m0 + wm + mi * 16 + (fc << 2) + r;
        const int n = n0 + wn + ni * 16 + fr;
        const float v = acc[mi][ni][r];
        const int b = m >> 11, s = m & (S_ - 1), h = n >> 6, d = n & 63;
        if (z != 2) {
          outp[((((size_t)b * H_ + h) * S_ + s) << 6) + d] = f2bf(v);
        } else {
          outp[(((size_t)b * H_ + h) * D_ + d) * S_ + s] = f2bf(v);
        }
      }
}

// ---------------- output projection GEMM (pipelined + swizzled, BM=64) -----
__global__ __launch_bounds__(256, 4) void oproj_gemm(
    const u16* __restrict__ A, const u16* __restrict__ Bt,
    const float* __restrict__ bias, float* __restrict__ outp) {
  constexpr int BM = 64, BN = 128, BK = 32;
  __shared__ alignas(16) u16 As[3][BM * BK];
  __shared__ alignas(16) u16 Bs[3][BN * BK];

  const int wg = blockIdx.x;           // 0..511, xcd-bucketed
  const int xcd = wg & 7, idx = wg >> 3;
  const int nb = idx & 7, mi_ = idx >> 3;
  const int m0 = (xcd * 8 + mi_) * BM, n0 = nb * BN;

  const int tid = threadIdx.x;
  const int wave = tid >> 6, lane = tid & 63;
  const int wm = (wave >> 1) * 32, wn = (wave & 1) * 64;
  const int fr = lane & 15, fc = lane >> 4;
  const int lrow = lane >> 2;
  const int lcol_sw = (((lane & 3) ^ ((lrow >> 1) & 3)) * 8);

  f32x4 acc[2][4] = {};

  u16 *aA = As[0], *aB = As[1], *aC = As[2];
  u16 *bA = Bs[0], *bB = Bs[1], *bC = Bs[2];

  auto stage = [&](int k0, u16* as, u16* bs) {
#pragma unroll
    for (int i = 0; i < 3; ++i) {
      const int c = wave + 4 * i;
      if (c < 4)
        gload16(A + (size_t)(m0 + c * 16 + lrow) * E_ + k0 + lcol_sw, as + c * 16 * BK);
      else
        gload16(Bt + (size_t)(n0 + (c - 4) * 16 + lrow) * E_ + k0 + lcol_sw,
                bs + (c - 4) * 16 * BK);
    }
  };

  constexpr int NK = E_ / BK;  // 32
  stage(0, aA, bA);
  stage(BK, aB, bB);

  const int sl = (fc ^ ((fr >> 1) & 3)) * 8;

  for (int t = 0; t < NK; ++t) {
    if (t + 1 < NK) {
      asm volatile("s_waitcnt vmcnt(3)" ::: "memory");
    } else {
      asm volatile("s_waitcnt vmcnt(0)" ::: "memory");
    }
    __builtin_amdgcn_s_barrier();
    __builtin_amdgcn_sched_barrier(0);

    if (t + 2 < NK) stage((t + 2) * BK, aC, bC);

    bf16x8 af[2], bfr[4];
#pragma unroll
    for (int mi = 0; mi < 2; ++mi)
      af[mi] = *(const bf16x8*)&aA[(wm + mi * 16 + fr) * BK + sl];
#pragma unroll
    for (int ni = 0; ni < 4; ++ni)
      bfr[ni] = *(const bf16x8*)&bA[(wn + ni * 16 + fr) * BK + sl];
    __builtin_amdgcn_s_setprio(1);
#pragma unroll
    for (int mi = 0; mi < 2; ++mi)
#pragma unroll
      for (int ni = 0; ni < 4; ++ni)
        acc[mi][ni] = mfma16(af[mi], bfr[ni], acc[mi][ni]);
    __builtin_amdgcn_s_setprio(0);

    u16* tp;
    tp = aA; aA = aB; aB = aC; aC = tp;
    tp = bA; bA = bB; bB = bC; bC = tp;
  }

#pragma unroll
  for (int mi = 0; mi < 2; ++mi)
#pragma unroll
    for (int ni = 0; ni < 4; ++ni)
#pragma unroll
      for (int r = 0; r < 4; ++r) {
        const int m = m0 + wm + mi * 16 + (fc << 2) + r;
        const int n = n0 + wn + ni * 16 + fr;
        outp[(size_t)m * E_ + n] = acc[mi][ni][r] + bias[n];
      }
}

// ---------------- causal flash attention (r13: 8-wave QBLK=128) -------------
__device__ __forceinline__ void stage_kv8(
    const u16* __restrict__ Kh_head, const u16* __restrict__ Vt_head,
    int kv0, u16* kb, u16* vb, int wq, int lane) {
  gload16(Kh_head + (size_t)(kv0 + lane) * D_ + wq * 8, kb + wq * 512);
  gload16(Vt_head + (size_t)lane * S_ + kv0 + wq * 8, vb + wq * 512);
}

__global__ __launch_bounds__(512, 4) void flash_attn(
    const u16* __restrict__ Qh, const u16* __restrict__ Kh,
    const u16* __restrict__ Vt, u16* __restrict__ O) {
  __shared__ alignas(16) u16 Kb[3][4096];
  __shared__ alignas(16) u16 Vb[3][4096];

  const int i = blockIdx.x;            // 0..511, snake pairing
  const int ch = i >> 8, p = i & 255;
  const int j = (ch << 8) + ((ch & 1) ? (255 - p) : p);
  const int qt = 15 - (j >> 5);
  const int bh = j & 31;

  const int tid = threadIdx.x;
  const int wq = tid >> 6, lane = tid & 63;

  const int q0 = qt * 128;
  const int b = bh >> 4, h = bh & 15;
  constexpr float SC = 0.125f * 1.4426950408889634f;
  const int fr = lane & 15, fc = lane >> 4;

  const u16* Qbase = Qh + ((size_t)bh * S_ + q0 + wq * 16 + fr) * D_ + 8 * fc;
  const bf16x8 qf0 = *(const bf16x8*)Qbase;
  const bf16x8 qf1 = *(const bf16x8*)(Qbase + 32);
  const u16* Kh_head = Kh + (size_t)bh * S_ * D_;
  const u16* Vt_head = Vt + (size_t)bh * D_ * S_;

  float lacc = 0.f;
  f32x4 oacc[4] = {};
  const int nt = 2 * qt + 2;

  u16 *kA = Kb[0], *kB = Kb[1], *kC = Kb[2];
  u16 *vA = Vb[0], *vB = Vb[1], *vC = Vb[2];

  stage_kv8(Kh_head, Vt_head, 0, kA, vA, wq, lane);
  stage_kv8(Kh_head, Vt_head, 64, kB, vB, wq, lane);

  for (int t = 0; t < nt; ++t) {
    if (t + 1 < nt) {
      asm volatile("s_waitcnt vmcnt(2)" ::: "memory");
    } else {
      asm volatile("s_waitcnt vmcnt(0)" ::: "memory");
    }
    __builtin_amdgcn_s_barrier();
    __builtin_amdgcn_sched_barrier(0);

    if (t + 2 < nt)
      stage_kv8(Kh_head, Vt_head, (t + 2) * 64, kC, vC, wq, lane);

    const u16* kb = kA;
    const u16* vb = vA;

    f32x4 sacc[4] = {};
    __builtin_amdgcn_s_setprio(1);
#pragma unroll
    for (int ni = 0; ni < 4; ++ni) {
      const bf16x8 k0 = *(const bf16x8*)&kb[fc * 512 + (16 * ni + fr) * 8];
      const bf16x8 k1 = *(const bf16x8*)&kb[(fc + 4) * 512 + (16 * ni + fr) * 8];
      sacc[ni] = mfma16(k0, qf0, sacc[ni]);
      sacc[ni] = mfma16(k1, qf1, sacc[ni]);
    }
    __builtin_amdgcn_s_setprio(0);

    const bool diag = (t >= nt - 2);
    const int qg = q0 + wq * 16 + fr;
    const int kvb = t * 64;
#pragma unroll
    for (int ni = 0; ni < 4; ++ni)
#pragma unroll
      for (int r = 0; r < 4; ++r) {
        const int kvg = kvb + 16 * ni + 4 * fc + r;
        float pv;
        if (diag && kvg > qg) {
          pv = 0.f;
        } else {
          pv = __builtin_amdgcn_exp2f(sacc[ni][r] * SC);
        }
        sacc[ni][r] = pv;
        lacc += pv;
      }

    unsigned w[4][2];
#pragma unroll
    for (int ni = 0; ni < 4; ++ni) {
      asm("v_cvt_pk_bf16_f32 %0, %1, %2"
          : "=v"(w[ni][0]) : "v"(sacc[ni][0]), "v"(sacc[ni][1]));
      asm("v_cvt_pk_bf16_f32 %0, %1, %2"
          : "=v"(w[ni][1]) : "v"(sacc[ni][2]), "v"(sacc[ni][3]));
    }

    unsigned paw0[4], paw1[4];
#pragma unroll
    for (int pair = 0; pair < 2; ++pair) {
      unsigned xx[2], yy[2], tt[2];
#pragma unroll
      for (int hh = 0; hh < 2; ++hh) {
        unsigned a = w[2 * pair][hh], bb = w[2 * pair + 1][hh];
        asm volatile("v_permlane32_swap_b32 %0, %1" : "+v"(a), "+v"(bb));
        xx[hh] = a; yy[hh] = bb;
        const unsigned s = (fc & 1) ? a : bb;
        tt[hh] = (unsigned)__shfl_xor((int)s, 16);
      }
      unsigned* pw_ = pair ? paw1 : paw0;
      pw_[0] = (fc & 1) ? tt[0] : xx[0];
      pw_[1] = (fc & 1) ? tt[1] : xx[1];
      pw_[2] = (fc & 1) ? yy[0] : tt[0];
      pw_[3] = (fc & 1) ? yy[1] : tt[1];
    }
    bf16x8 pa0, pa1;
    {
      u32x4 t0 = {paw0[0], paw0[1], paw0[2], paw0[3]};
      u32x4 t1 = {paw1[0], paw1[1], paw1[2], paw1[3]};
      __builtin_memcpy(&pa0, &t0, 16);
      __builtin_memcpy(&pa1, &t1, 16);
    }

    __builtin_amdgcn_s_setprio(1);
#pragma unroll
    for (int nd = 0; nd < 4; ++nd) {
      const bf16x8 v0 = *(const bf16x8*)&vb[fc * 512 + (16 * nd + fr) * 8];
      const bf16x8 v1 = *(const bf16x8*)&vb[(fc + 4) * 512 + (16 * nd + fr) * 8];
      oacc[nd] = mfma16(pa0, v0, oacc[nd]);
      oacc[nd] = mfma16(pa1, v1, oacc[nd]);
    }
    __builtin_amdgcn_s_setprio(0);

    u16* tk = kA; kA = kB; kB = kC; kC = tk;
    u16* tv = vA; vA = vB; vB = vC; vC = tv;
  }

  float l = lacc;
  l += __shfl_xor(l, 16);
  l += __shfl_xor(l, 32);
  float linv[4];
#pragma unroll
  for (int r = 0; r < 4; ++r)
    linv[r] = __builtin_amdgcn_rcpf(__shfl(l, 4 * fc + r));

#pragma unroll
  for (int nd = 0; nd < 4; ++nd) {
#pragma unroll
    for (int r = 0; r < 4; ++r) {
      const int qr = q0 + wq * 16 + (fc << 2) + r;
      const int d = 16 * nd + fr;
      const float v = oacc[nd][r] * linv[r];
      O[((size_t)b * S_ + qr) * E_ + h * D_ + d] = f2bf(v);
    }
  }
}

// ---------------------------------------------------------------------------
extern "C" void kernel_launch(void* const* d_in, const int* in_sizes, int n_in,
                              void* d_out, int out_size, void* d_ws, size_t ws_size,
                              hipStream_t stream) {
  const float* q  = (const float*)d_in[0];
  const float* k  = (const float*)d_in[1];
  const float* v  = (const float*)d_in[2];
  const float* Wq = (const float*)d_in[3];
  const float* Wk = (const float*)d_in[4];
  const float* Wv = (const float*)d_in[5];
  const float* Wo = (const float*)d_in[6];
  const float* bo = (const float*)d_in[7];

  const size_t nBSE = (size_t)M_ * E_;  // 4M elems
  const size_t nEE  = (size_t)E_ * E_;  // 1M elems
  u16* Wqb = (u16*)d_ws;
  u16* Wkb = Wqb + nEE;
  u16* Wvb = Wkb + nEE;
  u16* Wob = Wvb + nEE;
  u16* Qh  = Wob + nEE;
  u16* Kh  = Qh + nBSE;
  u16* Vt  = Kh + nBSE;
  u16* Oa  = Vt + nBSE;

  CvtArgs ca;
  ca.src[0] = Wq; ca.dst[0] = Wqb; ca.n[0] = (int)nEE;
  ca.src[1] = Wk; ca.dst[1] = Wkb; ca.n[1] = (int)nEE;
  ca.src[2] = Wv; ca.dst[2] = Wvb; ca.n[2] = (int)nEE;
  ca.src[3] = Wo; ca.dst[3] = Wob; ca.n[3] = (int)nEE;
  cvt_kernel<<<dim3(256, 4), 256, 0, stream>>>(ca);

  // Fused Q/K/V projections reading fp32 inputs directly: 768 blocks
  qkv_gemm<<<dim3(768), 256, 0, stream>>>(
      q, k, v, Wqb, Wkb, Wvb, Qh, Kh, Vt);
  // 512 blocks x 512 threads: one 128-row q-tile each, snake pairing
  flash_attn<<<dim3(512), 512, 0, stream>>>(Qh, Kh, Vt, Oa);
  // O-projection: 512 blocks, xcd-bucketed, pipelined
  oproj_gemm<<<dim3(512), 256, 0, stream>>>(Oa, Wob, bo, (float*)d_out);
}